// Round 1
// baseline (1146.770 us; speedup 1.0000x reference)
//
#include <hip/hip_runtime.h>
#include <cstdint>

// ============================================================================
// ParallelTransformerBlock (PaLM-style parallel attn+FF, MQA, RoPE, LoRA)
// B=2, N=2048, DIM=2048, HEADS=16, DIM_HEAD=64 (MQA: k/v single head),
// FF_INNER=8192, LORA_R=8.  All inputs f32; compute in bf16 MFMA (threshold
// is the bf16 floor 9.19e-2).
//
// Pipeline:
//   ln_kernel        : x -> xn (bf16), per-token LN
//   transpose_wf     : w_fused^T -> bf16, LoRA q/k/v folded in (rank-8 update)
//   transpose_w2     : [w_ff_out ; w_attn_out + lora_o] ^T -> bf16 (K-concat)
//   gemm1            : xn @ w_fused ; qkv cols -> f32 buf, ff cols -> two-pass
//                      (gate then x_ff) with silu fused -> A2[:, 0:8192] bf16
//   qkv_prep         : rope(q)*scale, rope(k), v -> MFMA-friendly layouts
//   attn_kernel      : causal MQA flash attention -> A2[:, 8192:9216] bf16
//   gemm2            : A2 @ [w_ff;w_attn]^T -> d_out f32 (single write)
//
// GEMM core: m97 structure (128x128 tile, BK=32, global_load_lds width16,
// v_mfma_f32_16x16x32_bf16). Layouts: A row-major (m,k); B passed as B^T
// row-major (n,k). C/D: col=lane&15, row=quad*4+reg. A: m=lane&15,
// k=quad*8+j.
// ============================================================================

typedef __bf16 bf16_t;
typedef __bf16 bf16x8 __attribute__((ext_vector_type(8)));
typedef float f32x4 __attribute__((ext_vector_type(4)));

#define LOG2E 1.44269504088896340736f

__device__ __forceinline__ void gload_lds16(const void* g, void* l) {
  // async global->LDS, 16B/lane; LDS dest is wave-uniform base + lane*16
  __builtin_amdgcn_global_load_lds(
      (__attribute__((address_space(1))) void*)(uintptr_t)g,
      (__attribute__((address_space(3))) void*)(uint32_t)(uintptr_t)l,
      16, 0, 0);
}

__device__ __forceinline__ f32x4 mfma16(bf16x8 a, bf16x8 b, f32x4 c) {
  return __builtin_amdgcn_mfma_f32_16x16x32_bf16(a, b, c, 0, 0, 0);
}

// ---------------------------------------------------------------------------
// LayerNorm: one block per token row (4096 rows x 2048)
// ---------------------------------------------------------------------------
__global__ __launch_bounds__(256) void ln_kernel(
    const float* __restrict__ x, const float* __restrict__ gamma,
    bf16_t* __restrict__ xn)
{
  const int row = blockIdx.x;
  const int t = threadIdx.x;
  const float4* xr = (const float4*)(x + (size_t)row * 2048);
  float4 a = xr[t * 2];
  float4 b = xr[t * 2 + 1];
  float s  = a.x + a.y + a.z + a.w + b.x + b.y + b.z + b.w;
  float ss = a.x*a.x + a.y*a.y + a.z*a.z + a.w*a.w
           + b.x*b.x + b.y*b.y + b.z*b.z + b.w*b.w;
  #pragma unroll
  for (int m = 1; m < 64; m <<= 1) {
    s  += __shfl_xor(s, m);
    ss += __shfl_xor(ss, m);
  }
  __shared__ float red[8];
  const int wave = t >> 6, lane = t & 63;
  if (lane == 0) { red[wave] = s; red[4 + wave] = ss; }
  __syncthreads();
  const float stot  = red[0] + red[1] + red[2] + red[3];
  const float sstot = red[4] + red[5] + red[6] + red[7];
  const float mu  = stot * (1.f / 2048.f);
  const float var = sstot * (1.f / 2048.f) - mu * mu;
  const float rs  = rsqrtf(var + 1e-5f);
  float v[8] = {a.x, a.y, a.z, a.w, b.x, b.y, b.z, b.w};
  bf16x8 o;
  #pragma unroll
  for (int e = 0; e < 8; ++e)
    o[e] = (bf16_t)((v[e] - mu) * rs * gamma[t * 8 + e]);
  *(bf16x8*)(xn + (size_t)row * 2048 + t * 8) = o;
}

// ---------------------------------------------------------------------------
// Transpose+convert w_fused (2048 x 17536 f32) -> wfT (17536 x 2048 bf16),
// folding lora_q/k/v (W += A@B) into cols [0,1152). 64x64 tiles, LDS pad +1.
// n-segments are 64-aligned so the lora branch is block-uniform.
// ---------------------------------------------------------------------------
__global__ __launch_bounds__(256) void transpose_wf_kernel(
    const float* __restrict__ w,
    const float* __restrict__ qa, const float* __restrict__ qb,
    const float* __restrict__ ka, const float* __restrict__ kb,
    const float* __restrict__ va, const float* __restrict__ vb,
    bf16_t* __restrict__ wfT)
{
  __shared__ float tile[64][65];
  const int t  = threadIdx.x;
  const int n0 = blockIdx.x * 64;
  const int k0 = blockIdx.y * 64;
  #pragma unroll
  for (int it = 0; it < 4; ++it) {
    const int kr = (t >> 4) + it * 16;
    const float4 vv = *(const float4*)(w + (size_t)(k0 + kr) * 17536 + n0 + (t & 15) * 4);
    tile[kr][(t & 15) * 4 + 0] = vv.x;
    tile[kr][(t & 15) * 4 + 1] = vv.y;
    tile[kr][(t & 15) * 4 + 2] = vv.z;
    tile[kr][(t & 15) * 4 + 3] = vv.w;
  }
  __syncthreads();
  const float* la = nullptr; const float* lb = nullptr;
  int nbo = 0, ldlb = 0;
  if (n0 < 1024)      { la = qa; lb = qb; nbo = n0;        ldlb = 1024; }
  else if (n0 < 1088) { la = ka; lb = kb; nbo = n0 - 1024; ldlb = 64;   }
  else if (n0 < 1152) { la = va; lb = vb; nbo = n0 - 1088; ldlb = 64;   }
  #pragma unroll
  for (int it = 0; it < 2; ++it) {
    const int nl = (t >> 3) + it * 32;
    const int kl = (t & 7) * 8;
    float vals[8];
    #pragma unroll
    for (int e = 0; e < 8; ++e) vals[e] = tile[kl + e][nl];
    if (la) {
      float bc[8];
      #pragma unroll
      for (int r = 0; r < 8; ++r) bc[r] = lb[r * ldlb + nbo + nl];
      #pragma unroll
      for (int e = 0; e < 8; ++e) {
        const float* ar = la + (size_t)(k0 + kl + e) * 8;
        float d = 0.f;
        #pragma unroll
        for (int r = 0; r < 8; ++r) d += ar[r] * bc[r];
        vals[e] += d;
      }
    }
    bf16x8 o;
    #pragma unroll
    for (int e = 0; e < 8; ++e) o[e] = (bf16_t)vals[e];
    *(bf16x8*)(wfT + (size_t)(n0 + nl) * 2048 + k0 + kl) = o;
  }
}

// ---------------------------------------------------------------------------
// Build w2T (2048 x 9216 bf16): cols [0,8192) = w_ff_out^T,
// cols [8192,9216) = (w_attn_out + lora_o_a@lora_o_b)^T.
// ---------------------------------------------------------------------------
__global__ __launch_bounds__(256) void transpose_w2_kernel(
    const float* __restrict__ wff,   // 8192 x 2048
    const float* __restrict__ watt,  // 1024 x 2048
    const float* __restrict__ oa, const float* __restrict__ ob,
    bf16_t* __restrict__ w2T)
{
  __shared__ float tile[64][65];
  const int t  = threadIdx.x;
  const int n0 = blockIdx.x * 64;
  const int k0 = blockIdx.y * 64;          // 0..9152
  const bool isatt = (k0 >= 8192);
  const float* src = isatt ? (watt + (size_t)(k0 - 8192) * 2048)
                           : (wff + (size_t)k0 * 2048);
  #pragma unroll
  for (int it = 0; it < 4; ++it) {
    const int kr = (t >> 4) + it * 16;
    const float4 vv = *(const float4*)(src + (size_t)kr * 2048 + n0 + (t & 15) * 4);
    tile[kr][(t & 15) * 4 + 0] = vv.x;
    tile[kr][(t & 15) * 4 + 1] = vv.y;
    tile[kr][(t & 15) * 4 + 2] = vv.z;
    tile[kr][(t & 15) * 4 + 3] = vv.w;
  }
  __syncthreads();
  #pragma unroll
  for (int it = 0; it < 2; ++it) {
    const int nl = (t >> 3) + it * 32;
    const int kl = (t & 7) * 8;
    float vals[8];
    #pragma unroll
    for (int e = 0; e < 8; ++e) vals[e] = tile[kl + e][nl];
    if (isatt) {
      float bc[8];
      #pragma unroll
      for (int r = 0; r < 8; ++r) bc[r] = ob[r * 2048 + n0 + nl];
      #pragma unroll
      for (int e = 0; e < 8; ++e) {
        const float* ar = oa + (size_t)(k0 - 8192 + kl + e) * 8;
        float d = 0.f;
        #pragma unroll
        for (int r = 0; r < 8; ++r) d += ar[r] * bc[r];
        vals[e] += d;
      }
    }
    bf16x8 o;
    #pragma unroll
    for (int e = 0; e < 8; ++e) o[e] = (bf16_t)vals[e];
    *(bf16x8*)(w2T + (size_t)(n0 + nl) * 9216 + k0 + kl) = o;
  }
}

// ---------------------------------------------------------------------------
// GEMM core: C[128x128] += A[m0:,K] * BT[n0:,K]^T, bf16, f32 acc.
// 256 threads = 4 waves in 2x2; each wave does 4x4 16x16 frags.
// ---------------------------------------------------------------------------
__device__ __forceinline__ void gemm_core_128x128(
    const bf16_t* __restrict__ A, int ldA, int m0,
    const bf16_t* __restrict__ BT, int ldB, int n0,
    int K, bf16_t* As, bf16_t* Bs, f32x4* acc)
{
  const int t = threadIdx.x;
  const int wave = t >> 6;
  const int lane = t & 63;
  const int quad = lane >> 4;
  const int ln15 = lane & 15;
  const int wm = wave & 1, wn = wave >> 1;

  const bf16_t* gA = A + (size_t)(m0 + (t >> 2)) * ldA + ((t & 3) << 3);
  const bf16_t* gB = BT + (size_t)(n0 + (t >> 2)) * ldB + ((t & 3) << 3);
  char* lA = (char*)As + wave * 1024;
  char* lB = (char*)Bs + wave * 1024;
  const size_t sA64 = (size_t)64 * ldA;
  const size_t sB64 = (size_t)64 * ldB;
  const int aoff = (wm * 64 + ln15) * 32 + quad * 8;
  const int boff = (wn * 64 + ln15) * 32 + quad * 8;

  for (int kt = 0; kt < K; kt += 32) {
    gload_lds16(gA,        lA);
    gload_lds16(gA + sA64, lA + 4096);
    gload_lds16(gB,        lB);
    gload_lds16(gB + sB64, lB + 4096);
    gA += 32;
    gB += 32;
    __syncthreads();   // compiler emits vmcnt(0) drain before s_barrier
    bf16x8 a0 = *(const bf16x8*)(As + aoff);
    bf16x8 a1 = *(const bf16x8*)(As + aoff + 512);
    bf16x8 a2 = *(const bf16x8*)(As + aoff + 1024);
    bf16x8 a3 = *(const bf16x8*)(As + aoff + 1536);
    bf16x8 b0 = *(const bf16x8*)(Bs + boff);
    bf16x8 b1 = *(const bf16x8*)(Bs + boff + 512);
    bf16x8 b2 = *(const bf16x8*)(Bs + boff + 1024);
    bf16x8 b3 = *(const bf16x8*)(Bs + boff + 1536);
    acc[0]  = mfma16(a0, b0, acc[0]);
    acc[1]  = mfma16(a0, b1, acc[1]);
    acc[2]  = mfma16(a0, b2, acc[2]);
    acc[3]  = mfma16(a0, b3, acc[3]);
    acc[4]  = mfma16(a1, b0, acc[4]);
    acc[5]  = mfma16(a1, b1, acc[5]);
    acc[6]  = mfma16(a1, b2, acc[6]);
    acc[7]  = mfma16(a1, b3, acc[7]);
    acc[8]  = mfma16(a2, b0, acc[8]);
    acc[9]  = mfma16(a2, b1, acc[9]);
    acc[10] = mfma16(a2, b2, acc[10]);
    acc[11] = mfma16(a2, b3, acc[11]);
    acc[12] = mfma16(a3, b0, acc[12]);
    acc[13] = mfma16(a3, b1, acc[13]);
    acc[14] = mfma16(a3, b2, acc[14]);
    acc[15] = mfma16(a3, b3, acc[15]);
    __syncthreads();
  }
}

// ---------------------------------------------------------------------------
// GEMM1: fused = xn @ w_fused (K=2048). Col tiles: ct<9 -> q/k/v raw f32;
// ct>=9 -> ff pair (gate at +8192, x_ff), silu fused, bf16 -> A2[:,0:8192].
// ---------------------------------------------------------------------------
__global__ __launch_bounds__(256) void gemm1_kernel(
    const bf16_t* __restrict__ xn, const bf16_t* __restrict__ wfT,
    float* __restrict__ qkv, bf16_t* __restrict__ A2)
{
  __shared__ __align__(16) bf16_t As[128 * 32];
  __shared__ __align__(16) bf16_t Bs[128 * 32];
  const int m0 = blockIdx.x * 128;
  const int ct = blockIdx.y;
  const int t = threadIdx.x;
  const int wave = t >> 6, lane = t & 63;
  const int quad = lane >> 4, ln15 = lane & 15;
  const int wm = wave & 1, wn = wave >> 1;

  f32x4 acc[16];
  #pragma unroll
  for (int f = 0; f < 16; ++f) acc[f] = (f32x4){0.f, 0.f, 0.f, 0.f};

  if (ct < 9) {
    gemm_core_128x128(xn, 2048, m0, wfT, 2048, ct * 128, 2048, As, Bs, acc);
    const int rb = m0 + wm * 64 + quad * 4;
    const int cb = ct * 128 + wn * 64 + ln15;
    #pragma unroll
    for (int i = 0; i < 4; ++i)
      #pragma unroll
      for (int rr = 0; rr < 4; ++rr) {
        float* dst = qkv + (size_t)(rb + i * 16 + rr) * 1152 + cb;
        #pragma unroll
        for (int j = 0; j < 4; ++j) dst[j * 16] = acc[i * 4 + j][rr];
      }
  } else {
    const int c = ct - 9;
    // pass 1: gate tile (cols 9344 + c*128)
    gemm_core_128x128(xn, 2048, m0, wfT, 2048, 9344 + c * 128, 2048, As, Bs, acc);
    f32x4 sg[16];
    #pragma unroll
    for (int f = 0; f < 16; ++f) {
      #pragma unroll
      for (int rr = 0; rr < 4; ++rr) {
        float g = acc[f][rr];
        sg[f][rr] = g / (1.f + exp2f(-g * LOG2E));   // silu(g)
      }
      acc[f] = (f32x4){0.f, 0.f, 0.f, 0.f};
    }
    // pass 2: x_ff tile (cols 1152 + c*128)
    gemm_core_128x128(xn, 2048, m0, wfT, 2048, 1152 + c * 128, 2048, As, Bs, acc);
    const int rb = m0 + wm * 64 + quad * 4;
    const int cb = c * 128 + wn * 64 + ln15;
    #pragma unroll
    for (int i = 0; i < 4; ++i)
      #pragma unroll
      for (int rr = 0; rr < 4; ++rr) {
        bf16_t* dst = A2 + (size_t)(rb + i * 16 + rr) * 9216 + cb;
        #pragma unroll
        for (int j = 0; j < 4; ++j)
          dst[j * 16] = (bf16_t)(acc[i * 4 + j][rr] * sg[i * 4 + j][rr]);
      }
  }
}

// ---------------------------------------------------------------------------
// GEMM2: d_out = A2(4096x9216) @ w2T^T (N=2048). Writes f32 directly.
// ---------------------------------------------------------------------------
__global__ __launch_bounds__(256) void gemm2_kernel(
    const bf16_t* __restrict__ A2, const bf16_t* __restrict__ w2T,
    float* __restrict__ out)
{
  __shared__ __align__(16) bf16_t As[128 * 32];
  __shared__ __align__(16) bf16_t Bs[128 * 32];
  const int m0 = blockIdx.x * 128;
  const int n0 = blockIdx.y * 128;
  const int t = threadIdx.x;
  const int wave = t >> 6, lane = t & 63;
  const int quad = lane >> 4, ln15 = lane & 15;
  const int wm = wave & 1, wn = wave >> 1;

  f32x4 acc[16];
  #pragma unroll
  for (int f = 0; f < 16; ++f) acc[f] = (f32x4){0.f, 0.f, 0.f, 0.f};
  gemm_core_128x128(A2, 9216, m0, w2T, 9216, n0, 9216, As, Bs, acc);
  const int rb = m0 + wm * 64 + quad * 4;
  const int cb = n0 + wn * 64 + ln15;
  #pragma unroll
  for (int i = 0; i < 4; ++i)
    #pragma unroll
    for (int rr = 0; rr < 4; ++rr) {
      float* dst = out + (size_t)(rb + i * 16 + rr) * 2048 + cb;
      #pragma unroll
      for (int j = 0; j < 4; ++j) dst[j * 16] = acc[i * 4 + j][rr];
    }
}

// ---------------------------------------------------------------------------
// qkv_prep: one block per token. RoPE(q)*1/8 -> Q (b,h,n,64) bf16;
// RoPE(k) -> K (b,n,64) bf16; v -> Vt (b,64,n) bf16 (pre-transposed for PV).
// ---------------------------------------------------------------------------
__global__ __launch_bounds__(256) void qkv_prep_kernel(
    const float* __restrict__ qkv, bf16_t* __restrict__ Q,
    bf16_t* __restrict__ K, bf16_t* __restrict__ Vt)
{
  const int row = blockIdx.x;          // b*2048 + n
  const int t = threadIdx.x;
  const int b = row >> 11, n = row & 2047;
  __shared__ float buf[1152];
  const float4* src4 = (const float4*)(qkv + (size_t)row * 1152);
  for (int i = t; i < 288; i += 256) ((float4*)buf)[i] = src4[i];
  __syncthreads();

  const float fn = (float)n;
  // q: 4 elements per thread
  #pragma unroll
  for (int u = 0; u < 4; ++u) {
    const int e = t * 4 + u;           // 0..1023
    const int hd = e >> 6, d = e & 63;
    const float val = buf[e];
    const float rot = (d < 32) ? -buf[hd * 64 + d + 32] : buf[hd * 64 + d - 32];
    const int dm = d & 31;
    const float invf = exp2f(-(float)dm * (13.287712379549449f / 32.0f)); // 10000^(-dm/32)
    const float ang = fn * invf;
    float c, s;
    sincosf(ang, &s, &c);
    const float o = (val * c + rot * s) * 0.125f;   // * DIM_HEAD^-0.5
    Q[(((size_t)b * 16 + hd) * 2048 + n) * 64 + d] = (bf16_t)o;
  }
  if (t < 64) {
    const int d = t;
    const float val = buf[1024 + d];
    const float rot = (d < 32) ? -buf[1024 + d + 32] : buf[1024 + d - 32];
    const int dm = d & 31;
    const float invf = exp2f(-(float)dm * (13.287712379549449f / 32.0f));
    const float ang = fn * invf;
    float c, s;
    sincosf(ang, &s, &c);
    K[((size_t)b * 2048 + n) * 64 + d] = (bf16_t)(val * c + rot * s);
    Vt[((size_t)b * 64 + d) * 2048 + n] = (bf16_t)buf[1088 + d];
  }
}

// ---------------------------------------------------------------------------
// Causal MQA flash attention. Block = (qt, bh): Q-tile 128 rows, loop over
// 64-wide K/V tiles up to the diagonal. Wave w owns rows w*32..w*32+31
// (2x4 frags). P goes through per-wave LDS strip for C->A layout transform.
// Output -> A2[:, 8192 + h*64 + d].
// ---------------------------------------------------------------------------
__global__ __launch_bounds__(256) void attn_kernel(
    const bf16_t* __restrict__ Q, const bf16_t* __restrict__ Kg_,
    const bf16_t* __restrict__ Vt, bf16_t* __restrict__ A2)
{
  __shared__ __align__(16) bf16_t Qs[128 * 64];
  __shared__ __align__(16) bf16_t Ks[64 * 64];
  __shared__ __align__(16) bf16_t Vs[64 * 64];
  __shared__ __align__(16) bf16_t Ps[128 * 64];
  const int qt = blockIdx.x, bh = blockIdx.y;
  const int b = bh >> 4, h = bh & 15;
  const int qm0 = qt * 128;
  const int t = threadIdx.x;
  const int wave = t >> 6, lane = t & 63;
  const int quad = lane >> 4, ln15 = lane & 15;

  const bf16_t* Qg = Q + ((size_t)bh * 2048 + qm0) * 64;
  const bf16_t* Kg = Kg_ + (size_t)b * 2048 * 64;
  const bf16_t* Vg = Vt + (size_t)b * 64 * 2048;

  { // stage Q tile (16 KB, 4 rounds)
    const bf16_t* g = Qg + (size_t)(t >> 3) * 64 + ((t & 7) << 3);
    char* l = (char*)Qs + wave * 1024;
    gload_lds16(g,            l);
    gload_lds16(g + 32 * 64,  l + 4096);
    gload_lds16(g + 64 * 64,  l + 8192);
    gload_lds16(g + 96 * 64,  l + 12288);
  }

  float mstate[2][4], lstate[2][4];
  f32x4 o_acc[2][4];
  #pragma unroll
  for (int i = 0; i < 2; ++i)
    #pragma unroll
    for (int rr = 0; rr < 4; ++rr) { mstate[i][rr] = -1e30f; lstate[i][rr] = 0.f; }
  #pragma unroll
  for (int i = 0; i < 2; ++i)
    #pragma unroll
    for (int jd = 0; jd < 4; ++jd) o_acc[i][jd] = (f32x4){0.f, 0.f, 0.f, 0.f};

  const int njt = qt * 2 + 2;
  for (int jt = 0; jt < njt; ++jt) {
    { // stage K and Vt tiles (8 KB each, 2 rounds)
      const bf16_t* kg = Kg + (size_t)(jt * 64 + (t >> 3)) * 64 + ((t & 7) << 3);
      char* lk = (char*)Ks + wave * 1024;
      gload_lds16(kg,           lk);
      gload_lds16(kg + 32 * 64, lk + 4096);
      const bf16_t* vg = Vg + (size_t)(t >> 3) * 2048 + jt * 64 + ((t & 7) << 3);
      char* lv = (char*)Vs + wave * 1024;
      gload_lds16(vg,                   lv);
      gload_lds16(vg + (size_t)32*2048, lv + 4096);
    }
    __syncthreads();

    // S = Q K^T  (per wave: 2x4 frags, K=64)
    f32x4 sA[2][4];
    #pragma unroll
    for (int i = 0; i < 2; ++i)
      #pragma unroll
      for (int j = 0; j < 4; ++j) sA[i][j] = (f32x4){0.f, 0.f, 0.f, 0.f};
    #pragma unroll
    for (int ks = 0; ks < 2; ++ks) {
      bf16x8 aq0 = *(const bf16x8*)(Qs + (wave * 32 + ln15) * 64 + ks * 32 + quad * 8);
      bf16x8 aq1 = *(const bf16x8*)(Qs + (wave * 32 + 16 + ln15) * 64 + ks * 32 + quad * 8);
      #pragma unroll
      for (int j = 0; j < 4; ++j) {
        bf16x8 bk = *(const bf16x8*)(Ks + (j * 16 + ln15) * 64 + ks * 32 + quad * 8);
        sA[0][j] = mfma16(aq0, bk, sA[0][j]);
        sA[1][j] = mfma16(aq1, bk, sA[1][j]);
      }
    }

    const bool needmask = (jt * 64 + 63 > qm0 + wave * 32);
    #pragma unroll
    for (int i = 0; i < 2; ++i) {
      const int row0 = qm0 + wave * 32 + i * 16 + quad * 4;
      float alpha[4];
      #pragma unroll
      for (int rr = 0; rr < 4; ++rr) {
        const int rowg = row0 + rr;
        if (needmask) {
          #pragma unroll
          for (int j = 0; j < 4; ++j) {
            const int colg = jt * 64 + j * 16 + ln15;
            if (colg > rowg) sA[i][j][rr] = -1e30f;
          }
        }
        float mx = fmaxf(fmaxf(sA[i][0][rr], sA[i][1][rr]),
                         fmaxf(sA[i][2][rr], sA[i][3][rr]));
        mx = fmaxf(mx, __shfl_xor(mx, 1));
        mx = fmaxf(mx, __shfl_xor(mx, 2));
        mx = fmaxf(mx, __shfl_xor(mx, 4));
        mx = fmaxf(mx, __shfl_xor(mx, 8));
        const float mold = mstate[i][rr];
        const float mnew = fmaxf(mold, mx);
        const float al = exp2f((mold - mnew) * LOG2E);
        float rsum = 0.f;
        #pragma unroll
        for (int j = 0; j < 4; ++j) {
          const float p = exp2f((sA[i][j][rr] - mnew) * LOG2E);
          sA[i][j][rr] = p;
          rsum += p;
        }
        rsum += __shfl_xor(rsum, 1);
        rsum += __shfl_xor(rsum, 2);
        rsum += __shfl_xor(rsum, 4);
        rsum += __shfl_xor(rsum, 8);
        lstate[i][rr] = lstate[i][rr] * al + rsum;
        mstate[i][rr] = mnew;
        alpha[rr] = al;
      }
      #pragma unroll
      for (int jd = 0; jd < 4; ++jd)
        #pragma unroll
        for (int rr = 0; rr < 4; ++rr)
          o_acc[i][jd][rr] *= alpha[rr];
      // P (C-layout) -> per-wave LDS strip (A-layout source)
      #pragma unroll
      for (int j = 0; j < 4; ++j)
        #pragma unroll
        for (int rr = 0; rr < 4; ++rr)
          Ps[wave * 2048 + (i * 16 + quad * 4 + rr) * 64 + j * 16 + ln15] =
              (bf16_t)sA[i][j][rr];
    }

    // O += P @ V  (K = 64 keys)
    #pragma unroll
    for (int ks = 0; ks < 2; ++ks) {
      bf16x8 ap0 = *(const bf16x8*)(Ps + wave * 2048 + ln15 * 64 + ks * 32 + quad * 8);
      bf16x8 ap1 = *(const bf16x8*)(Ps + wave * 2048 + (16 + ln15) * 64 + ks * 32 + quad * 8);
      #pragma unroll
      for (int jd = 0; jd < 4; ++jd) {
        bf16x8 bv = *(const bf16x8*)(Vs + (jd * 16 + ln15) * 64 + ks * 32 + quad * 8);
        o_acc[0][jd] = mfma16(ap0, bv, o_acc[0][jd]);
        o_acc[1][jd] = mfma16(ap1, bv, o_acc[1][jd]);
      }
    }
    __syncthreads();
  }

  // epilogue: O / l -> A2[:, 8192 + h*64 + d]
  #pragma unroll
  for (int i = 0; i < 2; ++i) {
    const int row0 = qm0 + wave * 32 + i * 16 + quad * 4;
    #pragma unroll
    for (int rr = 0; rr < 4; ++rr) {
      const float inv = 1.f / lstate[i][rr];
      bf16_t* dst = A2 + ((size_t)b * 2048 + row0 + rr) * 9216 + 8192 + h * 64 + ln15;
      #pragma unroll
      for (int jd = 0; jd < 4; ++jd)
        dst[jd * 16] = (bf16_t)(o_acc[i][jd][rr] * inv);
    }
  }
}

// ---------------------------------------------------------------------------
extern "C" void kernel_launch(void* const* d_in, const int* in_sizes, int n_in,
                              void* d_out, int out_size, void* d_ws, size_t ws_size,
                              hipStream_t stream)
{
  const float* x      = (const float*)d_in[0];
  const float* gamma  = (const float*)d_in[1];
  const float* wfused = (const float*)d_in[2];
  const float* watt   = (const float*)d_in[3];
  const float* wff    = (const float*)d_in[4];
  const float* qa     = (const float*)d_in[5];
  const float* qb     = (const float*)d_in[6];
  const float* ka     = (const float*)d_in[7];
  const float* kb     = (const float*)d_in[8];
  const float* va     = (const float*)d_in[9];
  const float* vb     = (const float*)d_in[10];
  const float* oa     = (const float*)d_in[11];
  const float* ob     = (const float*)d_in[12];
  float* out = (float*)d_out;

  // workspace layout (bytes), total 230,162,432
  char* ws = (char*)d_ws;
  bf16_t* xn  = (bf16_t*)(ws);                    // 16,777,216  xn (4096x2048)
  bf16_t* wfT = (bf16_t*)(ws + 16777216);         // 71,827,456  w_fused^T+lora
  bf16_t* w2T = (bf16_t*)(ws + 88604672);         // 37,748,736  [wff;watt]^T
  float*  qkv = (float*)(ws + 126353408);         // 18,874,368  q/k/v raw f32
  bf16_t* A2  = (bf16_t*)(ws + 145227776);        // 75,497,472  [h | attn_out]
  bf16_t* Qr  = (bf16_t*)(ws + 220725248);        //  8,388,608  rope(q)/8
  bf16_t* Kr  = (bf16_t*)(ws + 229113856);        //    524,288  rope(k)
  bf16_t* Vtr = (bf16_t*)(ws + 229638144);        //    524,288  v^T

  ln_kernel<<<dim3(4096), dim3(256), 0, stream>>>(x, gamma, xn);
  transpose_wf_kernel<<<dim3(274, 32), dim3(256), 0, stream>>>(
      wfused, qa, qb, ka, kb, va, vb, wfT);
  transpose_w2_kernel<<<dim3(32, 144), dim3(256), 0, stream>>>(
      wff, watt, oa, ob, w2T);
  gemm1_kernel<<<dim3(32, 73), dim3(256), 0, stream>>>(xn, wfT, qkv, A2);
  qkv_prep_kernel<<<dim3(4096), dim3(256), 0, stream>>>(qkv, Qr, Kr, Vtr);
  attn_kernel<<<dim3(16, 32), dim3(256), 0, stream>>>(Qr, Kr, Vtr, A2);
  gemm2_kernel<<<dim3(32, 16), dim3(256), 0, stream>>>(A2, w2T, out);
}

// Round 2
// 1057.674 us; speedup vs baseline: 1.0842x; 1.0842x over previous
//
#include <hip/hip_runtime.h>
#include <cstdint>

// ============================================================================
// ParallelTransformerBlock (PaLM-style parallel attn+FF, MQA, RoPE, LoRA)
// B=2, N=2048, DIM=2048, HEADS=16, DIM_HEAD=64 (MQA), FF_INNER=8192, R=8.
//
// R1 change: gemm1 split into gemm1_qkv (128x128, as before) and gemm1_ff
// (dual-B K-loop: stage A once + gate-B + x-B, 32 MFMA/barrier, silu fused
// in epilogue from the two accumulator sets). Removes the double K-pass that
// held gemm1 at 622 TF (MfmaUtil 27%).
// ============================================================================

typedef __bf16 bf16_t;
typedef __bf16 bf16x8 __attribute__((ext_vector_type(8)));
typedef float f32x4 __attribute__((ext_vector_type(4)));

#define LOG2E 1.44269504088896340736f

__device__ __forceinline__ void gload_lds16(const void* g, void* l) {
  __builtin_amdgcn_global_load_lds(
      (__attribute__((address_space(1))) void*)(uintptr_t)g,
      (__attribute__((address_space(3))) void*)(uint32_t)(uintptr_t)l,
      16, 0, 0);
}

__device__ __forceinline__ f32x4 mfma16(bf16x8 a, bf16x8 b, f32x4 c) {
  return __builtin_amdgcn_mfma_f32_16x16x32_bf16(a, b, c, 0, 0, 0);
}

// ---------------------------------------------------------------------------
// LayerNorm: one block per token row (4096 rows x 2048)
// ---------------------------------------------------------------------------
__global__ __launch_bounds__(256) void ln_kernel(
    const float* __restrict__ x, const float* __restrict__ gamma,
    bf16_t* __restrict__ xn)
{
  const int row = blockIdx.x;
  const int t = threadIdx.x;
  const float4* xr = (const float4*)(x + (size_t)row * 2048);
  float4 a = xr[t * 2];
  float4 b = xr[t * 2 + 1];
  float s  = a.x + a.y + a.z + a.w + b.x + b.y + b.z + b.w;
  float ss = a.x*a.x + a.y*a.y + a.z*a.z + a.w*a.w
           + b.x*b.x + b.y*b.y + b.z*b.z + b.w*b.w;
  #pragma unroll
  for (int m = 1; m < 64; m <<= 1) {
    s  += __shfl_xor(s, m);
    ss += __shfl_xor(ss, m);
  }
  __shared__ float red[8];
  const int wave = t >> 6, lane = t & 63;
  if (lane == 0) { red[wave] = s; red[4 + wave] = ss; }
  __syncthreads();
  const float stot  = red[0] + red[1] + red[2] + red[3];
  const float sstot = red[4] + red[5] + red[6] + red[7];
  const float mu  = stot * (1.f / 2048.f);
  const float var = sstot * (1.f / 2048.f) - mu * mu;
  const float rs  = rsqrtf(var + 1e-5f);
  float v[8] = {a.x, a.y, a.z, a.w, b.x, b.y, b.z, b.w};
  bf16x8 o;
  #pragma unroll
  for (int e = 0; e < 8; ++e)
    o[e] = (bf16_t)((v[e] - mu) * rs * gamma[t * 8 + e]);
  *(bf16x8*)(xn + (size_t)row * 2048 + t * 8) = o;
}

// ---------------------------------------------------------------------------
// Transpose+convert w_fused (2048 x 17536 f32) -> wfT (17536 x 2048 bf16),
// folding lora_q/k/v into cols [0,1152). 64x64 tiles, LDS pad +1.
// ---------------------------------------------------------------------------
__global__ __launch_bounds__(256) void transpose_wf_kernel(
    const float* __restrict__ w,
    const float* __restrict__ qa, const float* __restrict__ qb,
    const float* __restrict__ ka, const float* __restrict__ kb,
    const float* __restrict__ va, const float* __restrict__ vb,
    bf16_t* __restrict__ wfT)
{
  __shared__ float tile[64][65];
  const int t  = threadIdx.x;
  const int n0 = blockIdx.x * 64;
  const int k0 = blockIdx.y * 64;
  #pragma unroll
  for (int it = 0; it < 4; ++it) {
    const int kr = (t >> 4) + it * 16;
    const float4 vv = *(const float4*)(w + (size_t)(k0 + kr) * 17536 + n0 + (t & 15) * 4);
    tile[kr][(t & 15) * 4 + 0] = vv.x;
    tile[kr][(t & 15) * 4 + 1] = vv.y;
    tile[kr][(t & 15) * 4 + 2] = vv.z;
    tile[kr][(t & 15) * 4 + 3] = vv.w;
  }
  __syncthreads();
  const float* la = nullptr; const float* lb = nullptr;
  int nbo = 0, ldlb = 0;
  if (n0 < 1024)      { la = qa; lb = qb; nbo = n0;        ldlb = 1024; }
  else if (n0 < 1088) { la = ka; lb = kb; nbo = n0 - 1024; ldlb = 64;   }
  else if (n0 < 1152) { la = va; lb = vb; nbo = n0 - 1088; ldlb = 64;   }
  #pragma unroll
  for (int it = 0; it < 2; ++it) {
    const int nl = (t >> 3) + it * 32;
    const int kl = (t & 7) * 8;
    float vals[8];
    #pragma unroll
    for (int e = 0; e < 8; ++e) vals[e] = tile[kl + e][nl];
    if (la) {
      float bc[8];
      #pragma unroll
      for (int r = 0; r < 8; ++r) bc[r] = lb[r * ldlb + nbo + nl];
      #pragma unroll
      for (int e = 0; e < 8; ++e) {
        const float* ar = la + (size_t)(k0 + kl + e) * 8;
        float d = 0.f;
        #pragma unroll
        for (int r = 0; r < 8; ++r) d += ar[r] * bc[r];
        vals[e] += d;
      }
    }
    bf16x8 o;
    #pragma unroll
    for (int e = 0; e < 8; ++e) o[e] = (bf16_t)vals[e];
    *(bf16x8*)(wfT + (size_t)(n0 + nl) * 2048 + k0 + kl) = o;
  }
}

// ---------------------------------------------------------------------------
// Build w2T (2048 x 9216 bf16): cols [0,8192) = w_ff_out^T,
// cols [8192,9216) = (w_attn_out + lora_o_a@lora_o_b)^T.
// ---------------------------------------------------------------------------
__global__ __launch_bounds__(256) void transpose_w2_kernel(
    const float* __restrict__ wff,   // 8192 x 2048
    const float* __restrict__ watt,  // 1024 x 2048
    const float* __restrict__ oa, const float* __restrict__ ob,
    bf16_t* __restrict__ w2T)
{
  __shared__ float tile[64][65];
  const int t  = threadIdx.x;
  const int n0 = blockIdx.x * 64;
  const int k0 = blockIdx.y * 64;          // 0..9152
  const bool isatt = (k0 >= 8192);
  const float* src = isatt ? (watt + (size_t)(k0 - 8192) * 2048)
                           : (wff + (size_t)k0 * 2048);
  #pragma unroll
  for (int it = 0; it < 4; ++it) {
    const int kr = (t >> 4) + it * 16;
    const float4 vv = *(const float4*)(src + (size_t)kr * 2048 + n0 + (t & 15) * 4);
    tile[kr][(t & 15) * 4 + 0] = vv.x;
    tile[kr][(t & 15) * 4 + 1] = vv.y;
    tile[kr][(t & 15) * 4 + 2] = vv.z;
    tile[kr][(t & 15) * 4 + 3] = vv.w;
  }
  __syncthreads();
  #pragma unroll
  for (int it = 0; it < 2; ++it) {
    const int nl = (t >> 3) + it * 32;
    const int kl = (t & 7) * 8;
    float vals[8];
    #pragma unroll
    for (int e = 0; e < 8; ++e) vals[e] = tile[kl + e][nl];
    if (isatt) {
      float bc[8];
      #pragma unroll
      for (int r = 0; r < 8; ++r) bc[r] = ob[r * 2048 + n0 + nl];
      #pragma unroll
      for (int e = 0; e < 8; ++e) {
        const float* ar = oa + (size_t)(k0 - 8192 + kl + e) * 8;
        float d = 0.f;
        #pragma unroll
        for (int r = 0; r < 8; ++r) d += ar[r] * bc[r];
        vals[e] += d;
      }
    }
    bf16x8 o;
    #pragma unroll
    for (int e = 0; e < 8; ++e) o[e] = (bf16_t)vals[e];
    *(bf16x8*)(w2T + (size_t)(n0 + nl) * 9216 + k0 + kl) = o;
  }
}

// ---------------------------------------------------------------------------
// GEMM core: C[128x128] += A[m0:,K] * BT[n0:,K]^T, bf16, f32 acc.
// ---------------------------------------------------------------------------
__device__ __forceinline__ void gemm_core_128x128(
    const bf16_t* __restrict__ A, int ldA, int m0,
    const bf16_t* __restrict__ BT, int ldB, int n0,
    int K, bf16_t* As, bf16_t* Bs, f32x4* acc)
{
  const int t = threadIdx.x;
  const int wave = t >> 6;
  const int lane = t & 63;
  const int quad = lane >> 4;
  const int ln15 = lane & 15;
  const int wm = wave & 1, wn = wave >> 1;

  const bf16_t* gA = A + (size_t)(m0 + (t >> 2)) * ldA + ((t & 3) << 3);
  const bf16_t* gB = BT + (size_t)(n0 + (t >> 2)) * ldB + ((t & 3) << 3);
  char* lA = (char*)As + wave * 1024;
  char* lB = (char*)Bs + wave * 1024;
  const size_t sA64 = (size_t)64 * ldA;
  const size_t sB64 = (size_t)64 * ldB;
  const int aoff = (wm * 64 + ln15) * 32 + quad * 8;
  const int boff = (wn * 64 + ln15) * 32 + quad * 8;

  for (int kt = 0; kt < K; kt += 32) {
    gload_lds16(gA,        lA);
    gload_lds16(gA + sA64, lA + 4096);
    gload_lds16(gB,        lB);
    gload_lds16(gB + sB64, lB + 4096);
    gA += 32;
    gB += 32;
    __syncthreads();
    bf16x8 a0 = *(const bf16x8*)(As + aoff);
    bf16x8 a1 = *(const bf16x8*)(As + aoff + 512);
    bf16x8 a2 = *(const bf16x8*)(As + aoff + 1024);
    bf16x8 a3 = *(const bf16x8*)(As + aoff + 1536);
    bf16x8 b0 = *(const bf16x8*)(Bs + boff);
    bf16x8 b1 = *(const bf16x8*)(Bs + boff + 512);
    bf16x8 b2 = *(const bf16x8*)(Bs + boff + 1024);
    bf16x8 b3 = *(const bf16x8*)(Bs + boff + 1536);
    acc[0]  = mfma16(a0, b0, acc[0]);
    acc[1]  = mfma16(a0, b1, acc[1]);
    acc[2]  = mfma16(a0, b2, acc[2]);
    acc[3]  = mfma16(a0, b3, acc[3]);
    acc[4]  = mfma16(a1, b0, acc[4]);
    acc[5]  = mfma16(a1, b1, acc[5]);
    acc[6]  = mfma16(a1, b2, acc[6]);
    acc[7]  = mfma16(a1, b3, acc[7]);
    acc[8]  = mfma16(a2, b0, acc[8]);
    acc[9]  = mfma16(a2, b1, acc[9]);
    acc[10] = mfma16(a2, b2, acc[10]);
    acc[11] = mfma16(a2, b3, acc[11]);
    acc[12] = mfma16(a3, b0, acc[12]);
    acc[13] = mfma16(a3, b1, acc[13]);
    acc[14] = mfma16(a3, b2, acc[14]);
    acc[15] = mfma16(a3, b3, acc[15]);
    __syncthreads();
  }
}

// ---------------------------------------------------------------------------
// GEMM1a (qkv cols 0..1151): raw f32 out to qkv buffer.
// ---------------------------------------------------------------------------
__global__ __launch_bounds__(256) void gemm1_qkv_kernel(
    const bf16_t* __restrict__ xn, const bf16_t* __restrict__ wfT,
    float* __restrict__ qkv)
{
  __shared__ __align__(16) bf16_t As[128 * 32];
  __shared__ __align__(16) bf16_t Bs[128 * 32];
  const int m0 = blockIdx.x * 128;
  const int ct = blockIdx.y;
  const int t = threadIdx.x;
  const int wave = t >> 6, lane = t & 63;
  const int quad = lane >> 4, ln15 = lane & 15;
  const int wm = wave & 1, wn = wave >> 1;

  f32x4 acc[16];
  #pragma unroll
  for (int f = 0; f < 16; ++f) acc[f] = (f32x4){0.f, 0.f, 0.f, 0.f};
  gemm_core_128x128(xn, 2048, m0, wfT, 2048, ct * 128, 2048, As, Bs, acc);
  const int rb = m0 + wm * 64 + quad * 4;
  const int cb = ct * 128 + wn * 64 + ln15;
  #pragma unroll
  for (int i = 0; i < 4; ++i)
    #pragma unroll
    for (int rr = 0; rr < 4; ++rr) {
      float* dst = qkv + (size_t)(rb + i * 16 + rr) * 1152 + cb;
      #pragma unroll
      for (int j = 0; j < 4; ++j) dst[j * 16] = acc[i * 4 + j][rr];
    }
}

// ---------------------------------------------------------------------------
// GEMM1b (ff): dual-B K-loop. Stage A once + gate-B (cols 9344+c*128) +
// x-B (cols 1152+c*128); 32 MFMA per barrier; epilogue writes
// silu(gate)*x -> A2[:, c*128 .. c*128+127] bf16.
// ---------------------------------------------------------------------------
__global__ __launch_bounds__(256, 2) void gemm1_ff_kernel(
    const bf16_t* __restrict__ xn, const bf16_t* __restrict__ wfT,
    bf16_t* __restrict__ A2)
{
  __shared__ __align__(16) bf16_t As[128 * 32];
  __shared__ __align__(16) bf16_t Bg[128 * 32];
  __shared__ __align__(16) bf16_t Bx[128 * 32];
  const int m0 = blockIdx.x * 128;
  const int c  = blockIdx.y;
  const int t = threadIdx.x;
  const int wave = t >> 6, lane = t & 63;
  const int quad = lane >> 4, ln15 = lane & 15;
  const int wm = wave & 1, wn = wave >> 1;

  const bf16_t* gA = xn  + (size_t)(m0 + (t >> 2)) * 2048 + ((t & 3) << 3);
  const bf16_t* gG = wfT + (size_t)(9344 + c * 128 + (t >> 2)) * 2048 + ((t & 3) << 3);
  const bf16_t* gX = wfT + (size_t)(1152 + c * 128 + (t >> 2)) * 2048 + ((t & 3) << 3);
  char* lA = (char*)As + wave * 1024;
  char* lG = (char*)Bg + wave * 1024;
  char* lX = (char*)Bx + wave * 1024;
  const size_t s64 = (size_t)64 * 2048;
  const int aoff = (wm * 64 + ln15) * 32 + quad * 8;
  const int boff = (wn * 64 + ln15) * 32 + quad * 8;

  f32x4 accg[16], accx[16];
  #pragma unroll
  for (int f = 0; f < 16; ++f) {
    accg[f] = (f32x4){0.f, 0.f, 0.f, 0.f};
    accx[f] = (f32x4){0.f, 0.f, 0.f, 0.f};
  }

  for (int kt = 0; kt < 2048; kt += 32) {
    gload_lds16(gA,       lA);
    gload_lds16(gA + s64, lA + 4096);
    gload_lds16(gG,       lG);
    gload_lds16(gG + s64, lG + 4096);
    gload_lds16(gX,       lX);
    gload_lds16(gX + s64, lX + 4096);
    gA += 32; gG += 32; gX += 32;
    __syncthreads();
    bf16x8 a0 = *(const bf16x8*)(As + aoff);
    bf16x8 a1 = *(const bf16x8*)(As + aoff + 512);
    bf16x8 a2 = *(const bf16x8*)(As + aoff + 1024);
    bf16x8 a3 = *(const bf16x8*)(As + aoff + 1536);
    bf16x8 g0 = *(const bf16x8*)(Bg + boff);
    bf16x8 g1 = *(const bf16x8*)(Bg + boff + 512);
    bf16x8 g2 = *(const bf16x8*)(Bg + boff + 1024);
    bf16x8 g3 = *(const bf16x8*)(Bg + boff + 1536);
    bf16x8 x0 = *(const bf16x8*)(Bx + boff);
    bf16x8 x1 = *(const bf16x8*)(Bx + boff + 512);
    bf16x8 x2 = *(const bf16x8*)(Bx + boff + 1024);
    bf16x8 x3 = *(const bf16x8*)(Bx + boff + 1536);
    accg[0]  = mfma16(a0, g0, accg[0]);
    accg[1]  = mfma16(a0, g1, accg[1]);
    accg[2]  = mfma16(a0, g2, accg[2]);
    accg[3]  = mfma16(a0, g3, accg[3]);
    accx[0]  = mfma16(a0, x0, accx[0]);
    accx[1]  = mfma16(a0, x1, accx[1]);
    accx[2]  = mfma16(a0, x2, accx[2]);
    accx[3]  = mfma16(a0, x3, accx[3]);
    accg[4]  = mfma16(a1, g0, accg[4]);
    accg[5]  = mfma16(a1, g1, accg[5]);
    accg[6]  = mfma16(a1, g2, accg[6]);
    accg[7]  = mfma16(a1, g3, accg[7]);
    accx[4]  = mfma16(a1, x0, accx[4]);
    accx[5]  = mfma16(a1, x1, accx[5]);
    accx[6]  = mfma16(a1, x2, accx[6]);
    accx[7]  = mfma16(a1, x3, accx[7]);
    accg[8]  = mfma16(a2, g0, accg[8]);
    accg[9]  = mfma16(a2, g1, accg[9]);
    accg[10] = mfma16(a2, g2, accg[10]);
    accg[11] = mfma16(a2, g3, accg[11]);
    accx[8]  = mfma16(a2, x0, accx[8]);
    accx[9]  = mfma16(a2, x1, accx[9]);
    accx[10] = mfma16(a2, x2, accx[10]);
    accx[11] = mfma16(a2, x3, accx[11]);
    accg[12] = mfma16(a3, g0, accg[12]);
    accg[13] = mfma16(a3, g1, accg[13]);
    accg[14] = mfma16(a3, g2, accg[14]);
    accg[15] = mfma16(a3, g3, accg[15]);
    accx[12] = mfma16(a3, x0, accx[12]);
    accx[13] = mfma16(a3, x1, accx[13]);
    accx[14] = mfma16(a3, x2, accx[14]);
    accx[15] = mfma16(a3, x3, accx[15]);
    __syncthreads();
  }

  const int rb = m0 + wm * 64 + quad * 4;
  const int cb = c * 128 + wn * 64 + ln15;
  #pragma unroll
  for (int i = 0; i < 4; ++i)
    #pragma unroll
    for (int rr = 0; rr < 4; ++rr) {
      bf16_t* dst = A2 + (size_t)(rb + i * 16 + rr) * 9216 + cb;
      #pragma unroll
      for (int j = 0; j < 4; ++j) {
        const float g = accg[i * 4 + j][rr];
        const float xv = accx[i * 4 + j][rr];
        dst[j * 16] = (bf16_t)(xv * (g / (1.f + exp2f(-g * LOG2E))));
      }
    }
}

// ---------------------------------------------------------------------------
// GEMM2: d_out = A2(4096x9216) @ w2T^T (N=2048). Writes f32 directly.
// ---------------------------------------------------------------------------
__global__ __launch_bounds__(256) void gemm2_kernel(
    const bf16_t* __restrict__ A2, const bf16_t* __restrict__ w2T,
    float* __restrict__ out)
{
  __shared__ __align__(16) bf16_t As[128 * 32];
  __shared__ __align__(16) bf16_t Bs[128 * 32];
  const int m0 = blockIdx.x * 128;
  const int n0 = blockIdx.y * 128;
  const int t = threadIdx.x;
  const int wave = t >> 6, lane = t & 63;
  const int quad = lane >> 4, ln15 = lane & 15;
  const int wm = wave & 1, wn = wave >> 1;

  f32x4 acc[16];
  #pragma unroll
  for (int f = 0; f < 16; ++f) acc[f] = (f32x4){0.f, 0.f, 0.f, 0.f};
  gemm_core_128x128(A2, 9216, m0, w2T, 9216, n0, 9216, As, Bs, acc);
  const int rb = m0 + wm * 64 + quad * 4;
  const int cb = n0 + wn * 64 + ln15;
  #pragma unroll
  for (int i = 0; i < 4; ++i)
    #pragma unroll
    for (int rr = 0; rr < 4; ++rr) {
      float* dst = out + (size_t)(rb + i * 16 + rr) * 2048 + cb;
      #pragma unroll
      for (int j = 0; j < 4; ++j) dst[j * 16] = acc[i * 4 + j][rr];
    }
}

// ---------------------------------------------------------------------------
// qkv_prep: one block per token. RoPE(q)*1/8 -> Q (b,h,n,64) bf16;
// RoPE(k) -> K (b,n,64) bf16; v -> Vt (b,64,n) bf16.
// ---------------------------------------------------------------------------
__global__ __launch_bounds__(256) void qkv_prep_kernel(
    const float* __restrict__ qkv, bf16_t* __restrict__ Q,
    bf16_t* __restrict__ K, bf16_t* __restrict__ Vt)
{
  const int row = blockIdx.x;          // b*2048 + n
  const int t = threadIdx.x;
  const int b = row >> 11, n = row & 2047;
  __shared__ float buf[1152];
  const float4* src4 = (const float4*)(qkv + (size_t)row * 1152);
  for (int i = t; i < 288; i += 256) ((float4*)buf)[i] = src4[i];
  __syncthreads();

  const float fn = (float)n;
  #pragma unroll
  for (int u = 0; u < 4; ++u) {
    const int e = t * 4 + u;           // 0..1023
    const int hd = e >> 6, d = e & 63;
    const float val = buf[e];
    const float rot = (d < 32) ? -buf[hd * 64 + d + 32] : buf[hd * 64 + d - 32];
    const int dm = d & 31;
    const float invf = exp2f(-(float)dm * (13.287712379549449f / 32.0f)); // 10000^(-dm/32)
    const float ang = fn * invf;
    float c, s;
    sincosf(ang, &s, &c);
    const float o = (val * c + rot * s) * 0.125f;
    Q[(((size_t)b * 16 + hd) * 2048 + n) * 64 + d] = (bf16_t)o;
  }
  if (t < 64) {
    const int d = t;
    const float val = buf[1024 + d];
    const float rot = (d < 32) ? -buf[1024 + d + 32] : buf[1024 + d - 32];
    const int dm = d & 31;
    const float invf = exp2f(-(float)dm * (13.287712379549449f / 32.0f));
    const float ang = fn * invf;
    float c, s;
    sincosf(ang, &s, &c);
    K[((size_t)b * 2048 + n) * 64 + d] = (bf16_t)(val * c + rot * s);
    Vt[((size_t)b * 64 + d) * 2048 + n] = (bf16_t)buf[1088 + d];
  }
}

// ---------------------------------------------------------------------------
// Causal MQA flash attention -> A2[:, 8192 + h*64 + d].
// ---------------------------------------------------------------------------
__global__ __launch_bounds__(256) void attn_kernel(
    const bf16_t* __restrict__ Q, const bf16_t* __restrict__ Kg_,
    const bf16_t* __restrict__ Vt, bf16_t* __restrict__ A2)
{
  __shared__ __align__(16) bf16_t Qs[128 * 64];
  __shared__ __align__(16) bf16_t Ks[64 * 64];
  __shared__ __align__(16) bf16_t Vs[64 * 64];
  __shared__ __align__(16) bf16_t Ps[128 * 64];
  const int qt = blockIdx.x, bh = blockIdx.y;
  const int b = bh >> 4, h = bh & 15;
  const int qm0 = qt * 128;
  const int t = threadIdx.x;
  const int wave = t >> 6, lane = t & 63;
  const int quad = lane >> 4, ln15 = lane & 15;

  const bf16_t* Qg = Q + ((size_t)bh * 2048 + qm0) * 64;
  const bf16_t* Kg = Kg_ + (size_t)b * 2048 * 64;
  const bf16_t* Vg = Vt + (size_t)b * 64 * 2048;

  {
    const bf16_t* g = Qg + (size_t)(t >> 3) * 64 + ((t & 7) << 3);
    char* l = (char*)Qs + wave * 1024;
    gload_lds16(g,            l);
    gload_lds16(g + 32 * 64,  l + 4096);
    gload_lds16(g + 64 * 64,  l + 8192);
    gload_lds16(g + 96 * 64,  l + 12288);
  }

  float mstate[2][4], lstate[2][4];
  f32x4 o_acc[2][4];
  #pragma unroll
  for (int i = 0; i < 2; ++i)
    #pragma unroll
    for (int rr = 0; rr < 4; ++rr) { mstate[i][rr] = -1e30f; lstate[i][rr] = 0.f; }
  #pragma unroll
  for (int i = 0; i < 2; ++i)
    #pragma unroll
    for (int jd = 0; jd < 4; ++jd) o_acc[i][jd] = (f32x4){0.f, 0.f, 0.f, 0.f};

  const int njt = qt * 2 + 2;
  for (int jt = 0; jt < njt; ++jt) {
    {
      const bf16_t* kg = Kg + (size_t)(jt * 64 + (t >> 3)) * 64 + ((t & 7) << 3);
      char* lk = (char*)Ks + wave * 1024;
      gload_lds16(kg,           lk);
      gload_lds16(kg + 32 * 64, lk + 4096);
      const bf16_t* vg = Vg + (size_t)(t >> 3) * 2048 + jt * 64 + ((t & 7) << 3);
      char* lv = (char*)Vs + wave * 1024;
      gload_lds16(vg,                   lv);
      gload_lds16(vg + (size_t)32*2048, lv + 4096);
    }
    __syncthreads();

    f32x4 sA[2][4];
    #pragma unroll
    for (int i = 0; i < 2; ++i)
      #pragma unroll
      for (int j = 0; j < 4; ++j) sA[i][j] = (f32x4){0.f, 0.f, 0.f, 0.f};
    #pragma unroll
    for (int ks = 0; ks < 2; ++ks) {
      bf16x8 aq0 = *(const bf16x8*)(Qs + (wave * 32 + ln15) * 64 + ks * 32 + quad * 8);
      bf16x8 aq1 = *(const bf16x8*)(Qs + (wave * 32 + 16 + ln15) * 64 + ks * 32 + quad * 8);
      #pragma unroll
      for (int j = 0; j < 4; ++j) {
        bf16x8 bk = *(const bf16x8*)(Ks + (j * 16 + ln15) * 64 + ks * 32 + quad * 8);
        sA[0][j] = mfma16(aq0, bk, sA[0][j]);
        sA[1][j] = mfma16(aq1, bk, sA[1][j]);
      }
    }

    const bool needmask = (jt * 64 + 63 > qm0 + wave * 32);
    #pragma unroll
    for (int i = 0; i < 2; ++i) {
      const int row0 = qm0 + wave * 32 + i * 16 + quad * 4;
      float alpha[4];
      #pragma unroll
      for (int rr = 0; rr < 4; ++rr) {
        const int rowg = row0 + rr;
        if (needmask) {
          #pragma unroll
          for (int j = 0; j < 4; ++j) {
            const int colg = jt * 64 + j * 16 + ln15;
            if (colg > rowg) sA[i][j][rr] = -1e30f;
          }
        }
        float mx = fmaxf(fmaxf(sA[i][0][rr], sA[i][1][rr]),
                         fmaxf(sA[i][2][rr], sA[i][3][rr]));
        mx = fmaxf(mx, __shfl_xor(mx, 1));
        mx = fmaxf(mx, __shfl_xor(mx, 2));
        mx = fmaxf(mx, __shfl_xor(mx, 4));
        mx = fmaxf(mx, __shfl_xor(mx, 8));
        const float mold = mstate[i][rr];
        const float mnew = fmaxf(mold, mx);
        const float al = exp2f((mold - mnew) * LOG2E);
        float rsum = 0.f;
        #pragma unroll
        for (int j = 0; j < 4; ++j) {
          const float p = exp2f((sA[i][j][rr] - mnew) * LOG2E);
          sA[i][j][rr] = p;
          rsum += p;
        }
        rsum += __shfl_xor(rsum, 1);
        rsum += __shfl_xor(rsum, 2);
        rsum += __shfl_xor(rsum, 4);
        rsum += __shfl_xor(rsum, 8);
        lstate[i][rr] = lstate[i][rr] * al + rsum;
        mstate[i][rr] = mnew;
        alpha[rr] = al;
      }
      #pragma unroll
      for (int jd = 0; jd < 4; ++jd)
        #pragma unroll
        for (int rr = 0; rr < 4; ++rr)
          o_acc[i][jd][rr] *= alpha[rr];
      #pragma unroll
      for (int j = 0; j < 4; ++j)
        #pragma unroll
        for (int rr = 0; rr < 4; ++rr)
          Ps[wave * 2048 + (i * 16 + quad * 4 + rr) * 64 + j * 16 + ln15] =
              (bf16_t)sA[i][j][rr];
    }

    #pragma unroll
    for (int ks = 0; ks < 2; ++ks) {
      bf16x8 ap0 = *(const bf16x8*)(Ps + wave * 2048 + ln15 * 64 + ks * 32 + quad * 8);
      bf16x8 ap1 = *(const bf16x8*)(Ps + wave * 2048 + (16 + ln15) * 64 + ks * 32 + quad * 8);
      #pragma unroll
      for (int jd = 0; jd < 4; ++jd) {
        bf16x8 bv = *(const bf16x8*)(Vs + (jd * 16 + ln15) * 64 + ks * 32 + quad * 8);
        o_acc[0][jd] = mfma16(ap0, bv, o_acc[0][jd]);
        o_acc[1][jd] = mfma16(ap1, bv, o_acc[1][jd]);
      }
    }
    __syncthreads();
  }

  #pragma unroll
  for (int i = 0; i < 2; ++i) {
    const int row0 = qm0 + wave * 32 + i * 16 + quad * 4;
    #pragma unroll
    for (int rr = 0; rr < 4; ++rr) {
      const float inv = 1.f / lstate[i][rr];
      bf16_t* dst = A2 + ((size_t)b * 2048 + row0 + rr) * 9216 + 8192 + h * 64 + ln15;
      #pragma unroll
      for (int jd = 0; jd < 4; ++jd)
        dst[jd * 16] = (bf16_t)(o_acc[i][jd][rr] * inv);
    }
  }
}

// ---------------------------------------------------------------------------
extern "C" void kernel_launch(void* const* d_in, const int* in_sizes, int n_in,
                              void* d_out, int out_size, void* d_ws, size_t ws_size,
                              hipStream_t stream)
{
  const float* x      = (const float*)d_in[0];
  const float* gamma  = (const float*)d_in[1];
  const float* wfused = (const float*)d_in[2];
  const float* watt   = (const float*)d_in[3];
  const float* wff    = (const float*)d_in[4];
  const float* qa     = (const float*)d_in[5];
  const float* qb     = (const float*)d_in[6];
  const float* ka     = (const float*)d_in[7];
  const float* kb     = (const float*)d_in[8];
  const float* va     = (const float*)d_in[9];
  const float* vb     = (const float*)d_in[10];
  const float* oa     = (const float*)d_in[11];
  const float* ob     = (const float*)d_in[12];
  float* out = (float*)d_out;

  char* ws = (char*)d_ws;
  bf16_t* xn  = (bf16_t*)(ws);                    // 16,777,216
  bf16_t* wfT = (bf16_t*)(ws + 16777216);         // 71,827,456
  bf16_t* w2T = (bf16_t*)(ws + 88604672);         // 37,748,736
  float*  qkv = (float*)(ws + 126353408);         // 18,874,368
  bf16_t* A2  = (bf16_t*)(ws + 145227776);        // 75,497,472
  bf16_t* Qr  = (bf16_t*)(ws + 220725248);        //  8,388,608
  bf16_t* Kr  = (bf16_t*)(ws + 229113856);        //    524,288
  bf16_t* Vtr = (bf16_t*)(ws + 229638144);        //    524,288

  ln_kernel<<<dim3(4096), dim3(256), 0, stream>>>(x, gamma, xn);
  transpose_wf_kernel<<<dim3(274, 32), dim3(256), 0, stream>>>(
      wfused, qa, qb, ka, kb, va, vb, wfT);
  transpose_w2_kernel<<<dim3(32, 144), dim3(256), 0, stream>>>(
      wff, watt, oa, ob, w2T);
  gemm1_qkv_kernel<<<dim3(32, 9), dim3(256), 0, stream>>>(xn, wfT, qkv);
  gemm1_ff_kernel<<<dim3(32, 64), dim3(256), 0, stream>>>(xn, wfT, A2);
  qkv_prep_kernel<<<dim3(4096), dim3(256), 0, stream>>>(qkv, Qr, Kr, Vtr);
  attn_kernel<<<dim3(16, 32), dim3(256), 0, stream>>>(Qr, Kr, Vtr, A2);
  gemm2_kernel<<<dim3(32, 16), dim3(256), 0, stream>>>(A2, w2T, out);
}

// Round 3
// 1009.562 us; speedup vs baseline: 1.1359x; 1.0477x over previous
//
#include <hip/hip_runtime.h>
#include <cstdint>

// ============================================================================
// ParallelTransformerBlock (PaLM-style parallel attn+FF, MQA, RoPE, LoRA)
// B=2, N=2048, DIM=2048, HEADS=16, DIM_HEAD=64 (MQA), FF_INNER=8192, R=8.
//
// R2 changes:
//  - gemm2: dual-B (two 128-col N tiles share one A tile, 32 MFMA/barrier)
//    + split-K=2 to keep 512 blocks (2/CU). f32 atomicAdd epilogue, d_out
//    zero-initialized with hipMemsetAsync.
//  - attn: Q-tile pairing (qt, 15-qt) -> uniform 34 K-tiles per block.
//  - gemm1_qkv: RoPE + Q/K/Vt layout fused into the epilogue (rotate partner
//    d+-32 is acc frag j^2 of the same lane). qkv f32 buffer + prep kernel
//    removed.
// ============================================================================

typedef __bf16 bf16_t;
typedef __bf16 bf16x8 __attribute__((ext_vector_type(8)));
typedef float f32x4 __attribute__((ext_vector_type(4)));

#define LOG2E 1.44269504088896340736f
#define LOG2_10K 13.287712379549449f   // log2(10000)

__device__ __forceinline__ void gload_lds16(const void* g, void* l) {
  __builtin_amdgcn_global_load_lds(
      (__attribute__((address_space(1))) void*)(uintptr_t)g,
      (__attribute__((address_space(3))) void*)(uint32_t)(uintptr_t)l,
      16, 0, 0);
}

__device__ __forceinline__ f32x4 mfma16(bf16x8 a, bf16x8 b, f32x4 c) {
  return __builtin_amdgcn_mfma_f32_16x16x32_bf16(a, b, c, 0, 0, 0);
}

// ---------------------------------------------------------------------------
// LayerNorm: one block per token row (4096 rows x 2048)
// ---------------------------------------------------------------------------
__global__ __launch_bounds__(256) void ln_kernel(
    const float* __restrict__ x, const float* __restrict__ gamma,
    bf16_t* __restrict__ xn)
{
  const int row = blockIdx.x;
  const int t = threadIdx.x;
  const float4* xr = (const float4*)(x + (size_t)row * 2048);
  float4 a = xr[t * 2];
  float4 b = xr[t * 2 + 1];
  float s  = a.x + a.y + a.z + a.w + b.x + b.y + b.z + b.w;
  float ss = a.x*a.x + a.y*a.y + a.z*a.z + a.w*a.w
           + b.x*b.x + b.y*b.y + b.z*b.z + b.w*b.w;
  #pragma unroll
  for (int m = 1; m < 64; m <<= 1) {
    s  += __shfl_xor(s, m);
    ss += __shfl_xor(ss, m);
  }
  __shared__ float red[8];
  const int wave = t >> 6, lane = t & 63;
  if (lane == 0) { red[wave] = s; red[4 + wave] = ss; }
  __syncthreads();
  const float stot  = red[0] + red[1] + red[2] + red[3];
  const float sstot = red[4] + red[5] + red[6] + red[7];
  const float mu  = stot * (1.f / 2048.f);
  const float var = sstot * (1.f / 2048.f) - mu * mu;
  const float rs  = rsqrtf(var + 1e-5f);
  float v[8] = {a.x, a.y, a.z, a.w, b.x, b.y, b.z, b.w};
  bf16x8 o;
  #pragma unroll
  for (int e = 0; e < 8; ++e)
    o[e] = (bf16_t)((v[e] - mu) * rs * gamma[t * 8 + e]);
  *(bf16x8*)(xn + (size_t)row * 2048 + t * 8) = o;
}

// ---------------------------------------------------------------------------
// Transpose+convert w_fused (2048 x 17536 f32) -> wfT (17536 x 2048 bf16),
// folding lora_q/k/v into cols [0,1152). 64x64 tiles, LDS pad +1.
// ---------------------------------------------------------------------------
__global__ __launch_bounds__(256) void transpose_wf_kernel(
    const float* __restrict__ w,
    const float* __restrict__ qa, const float* __restrict__ qb,
    const float* __restrict__ ka, const float* __restrict__ kb,
    const float* __restrict__ va, const float* __restrict__ vb,
    bf16_t* __restrict__ wfT)
{
  __shared__ float tile[64][65];
  const int t  = threadIdx.x;
  const int n0 = blockIdx.x * 64;
  const int k0 = blockIdx.y * 64;
  #pragma unroll
  for (int it = 0; it < 4; ++it) {
    const int kr = (t >> 4) + it * 16;
    const float4 vv = *(const float4*)(w + (size_t)(k0 + kr) * 17536 + n0 + (t & 15) * 4);
    tile[kr][(t & 15) * 4 + 0] = vv.x;
    tile[kr][(t & 15) * 4 + 1] = vv.y;
    tile[kr][(t & 15) * 4 + 2] = vv.z;
    tile[kr][(t & 15) * 4 + 3] = vv.w;
  }
  __syncthreads();
  const float* la = nullptr; const float* lb = nullptr;
  int nbo = 0, ldlb = 0;
  if (n0 < 1024)      { la = qa; lb = qb; nbo = n0;        ldlb = 1024; }
  else if (n0 < 1088) { la = ka; lb = kb; nbo = n0 - 1024; ldlb = 64;   }
  else if (n0 < 1152) { la = va; lb = vb; nbo = n0 - 1088; ldlb = 64;   }
  #pragma unroll
  for (int it = 0; it < 2; ++it) {
    const int nl = (t >> 3) + it * 32;
    const int kl = (t & 7) * 8;
    float vals[8];
    #pragma unroll
    for (int e = 0; e < 8; ++e) vals[e] = tile[kl + e][nl];
    if (la) {
      float bc[8];
      #pragma unroll
      for (int r = 0; r < 8; ++r) bc[r] = lb[r * ldlb + nbo + nl];
      #pragma unroll
      for (int e = 0; e < 8; ++e) {
        const float* ar = la + (size_t)(k0 + kl + e) * 8;
        float d = 0.f;
        #pragma unroll
        for (int r = 0; r < 8; ++r) d += ar[r] * bc[r];
        vals[e] += d;
      }
    }
    bf16x8 o;
    #pragma unroll
    for (int e = 0; e < 8; ++e) o[e] = (bf16_t)vals[e];
    *(bf16x8*)(wfT + (size_t)(n0 + nl) * 2048 + k0 + kl) = o;
  }
}

// ---------------------------------------------------------------------------
// Build w2T (2048 x 9216 bf16): cols [0,8192) = w_ff_out^T,
// cols [8192,9216) = (w_attn_out + lora_o_a@lora_o_b)^T.
// ---------------------------------------------------------------------------
__global__ __launch_bounds__(256) void transpose_w2_kernel(
    const float* __restrict__ wff,   // 8192 x 2048
    const float* __restrict__ watt,  // 1024 x 2048
    const float* __restrict__ oa, const float* __restrict__ ob,
    bf16_t* __restrict__ w2T)
{
  __shared__ float tile[64][65];
  const int t  = threadIdx.x;
  const int n0 = blockIdx.x * 64;
  const int k0 = blockIdx.y * 64;          // 0..9152
  const bool isatt = (k0 >= 8192);
  const float* src = isatt ? (watt + (size_t)(k0 - 8192) * 2048)
                           : (wff + (size_t)k0 * 2048);
  #pragma unroll
  for (int it = 0; it < 4; ++it) {
    const int kr = (t >> 4) + it * 16;
    const float4 vv = *(const float4*)(src + (size_t)kr * 2048 + n0 + (t & 15) * 4);
    tile[kr][(t & 15) * 4 + 0] = vv.x;
    tile[kr][(t & 15) * 4 + 1] = vv.y;
    tile[kr][(t & 15) * 4 + 2] = vv.z;
    tile[kr][(t & 15) * 4 + 3] = vv.w;
  }
  __syncthreads();
  #pragma unroll
  for (int it = 0; it < 2; ++it) {
    const int nl = (t >> 3) + it * 32;
    const int kl = (t & 7) * 8;
    float vals[8];
    #pragma unroll
    for (int e = 0; e < 8; ++e) vals[e] = tile[kl + e][nl];
    if (isatt) {
      float bc[8];
      #pragma unroll
      for (int r = 0; r < 8; ++r) bc[r] = ob[r * 2048 + n0 + nl];
      #pragma unroll
      for (int e = 0; e < 8; ++e) {
        const float* ar = oa + (size_t)(k0 - 8192 + kl + e) * 8;
        float d = 0.f;
        #pragma unroll
        for (int r = 0; r < 8; ++r) d += ar[r] * bc[r];
        vals[e] += d;
      }
    }
    bf16x8 o;
    #pragma unroll
    for (int e = 0; e < 8; ++e) o[e] = (bf16_t)vals[e];
    *(bf16x8*)(w2T + (size_t)(n0 + nl) * 9216 + k0 + kl) = o;
  }
}

// ---------------------------------------------------------------------------
// GEMM core: C[128x128] += A[m0:,K] * BT[n0:,K]^T, bf16, f32 acc.
// ---------------------------------------------------------------------------
__device__ __forceinline__ void gemm_core_128x128(
    const bf16_t* __restrict__ A, int ldA, int m0,
    const bf16_t* __restrict__ BT, int ldB, int n0,
    int K, bf16_t* As, bf16_t* Bs, f32x4* acc)
{
  const int t = threadIdx.x;
  const int wave = t >> 6;
  const int lane = t & 63;
  const int quad = lane >> 4;
  const int ln15 = lane & 15;
  const int wm = wave & 1, wn = wave >> 1;

  const bf16_t* gA = A + (size_t)(m0 + (t >> 2)) * ldA + ((t & 3) << 3);
  const bf16_t* gB = BT + (size_t)(n0 + (t >> 2)) * ldB + ((t & 3) << 3);
  char* lA = (char*)As + wave * 1024;
  char* lB = (char*)Bs + wave * 1024;
  const size_t sA64 = (size_t)64 * ldA;
  const size_t sB64 = (size_t)64 * ldB;
  const int aoff = (wm * 64 + ln15) * 32 + quad * 8;
  const int boff = (wn * 64 + ln15) * 32 + quad * 8;

  for (int kt = 0; kt < K; kt += 32) {
    gload_lds16(gA,        lA);
    gload_lds16(gA + sA64, lA + 4096);
    gload_lds16(gB,        lB);
    gload_lds16(gB + sB64, lB + 4096);
    gA += 32;
    gB += 32;
    __syncthreads();
    bf16x8 a0 = *(const bf16x8*)(As + aoff);
    bf16x8 a1 = *(const bf16x8*)(As + aoff + 512);
    bf16x8 a2 = *(const bf16x8*)(As + aoff + 1024);
    bf16x8 a3 = *(const bf16x8*)(As + aoff + 1536);
    bf16x8 b0 = *(const bf16x8*)(Bs + boff);
    bf16x8 b1 = *(const bf16x8*)(Bs + boff + 512);
    bf16x8 b2 = *(const bf16x8*)(Bs + boff + 1024);
    bf16x8 b3 = *(const bf16x8*)(Bs + boff + 1536);
    acc[0]  = mfma16(a0, b0, acc[0]);
    acc[1]  = mfma16(a0, b1, acc[1]);
    acc[2]  = mfma16(a0, b2, acc[2]);
    acc[3]  = mfma16(a0, b3, acc[3]);
    acc[4]  = mfma16(a1, b0, acc[4]);
    acc[5]  = mfma16(a1, b1, acc[5]);
    acc[6]  = mfma16(a1, b2, acc[6]);
    acc[7]  = mfma16(a1, b3, acc[7]);
    acc[8]  = mfma16(a2, b0, acc[8]);
    acc[9]  = mfma16(a2, b1, acc[9]);
    acc[10] = mfma16(a2, b2, acc[10]);
    acc[11] = mfma16(a2, b3, acc[11]);
    acc[12] = mfma16(a3, b0, acc[12]);
    acc[13] = mfma16(a3, b1, acc[13]);
    acc[14] = mfma16(a3, b2, acc[14]);
    acc[15] = mfma16(a3, b3, acc[15]);
    __syncthreads();
  }
}

// ---------------------------------------------------------------------------
// GEMM1a (qkv cols 0..1151) with fused RoPE + layout epilogue.
// ct<8: q cols (head = ct*2+wn). ct==8: wn=0 -> k, wn=1 -> v.
// Rotate partner d+-32 == acc frag (j^2), same lane/row.
// ---------------------------------------------------------------------------
__global__ __launch_bounds__(256) void gemm1_qkv_kernel(
    const bf16_t* __restrict__ xn, const bf16_t* __restrict__ wfT,
    bf16_t* __restrict__ Q, bf16_t* __restrict__ K, bf16_t* __restrict__ Vt)
{
  __shared__ __align__(16) bf16_t As[128 * 32];
  __shared__ __align__(16) bf16_t Bs[128 * 32];
  const int m0 = blockIdx.x * 128;
  const int ct = blockIdx.y;
  const int t = threadIdx.x;
  const int wave = t >> 6, lane = t & 63;
  const int quad = lane >> 4, ln15 = lane & 15;
  const int wm = wave & 1, wn = wave >> 1;

  f32x4 acc[16];
  #pragma unroll
  for (int f = 0; f < 16; ++f) acc[f] = (f32x4){0.f, 0.f, 0.f, 0.f};
  gemm_core_128x128(xn, 2048, m0, wfT, 2048, ct * 128, 2048, As, Bs, acc);

  const int rb = m0 + wm * 64 + quad * 4;
  const bool is_k = (ct == 8) && (wn == 0);
  const bool is_v = (ct == 8) && (wn == 1);
  // frequencies for d = j*16 + ln15: dm = d & 31 -> ln15 (j even), 16+ln15 (j odd)
  const float invf0 = exp2f(-(float)ln15 * (LOG2_10K / 32.0f));
  const float invf1 = exp2f(-(float)(16 + ln15) * (LOG2_10K / 32.0f));
  const int hd = ct * 2 + wn;   // head index when q

  #pragma unroll
  for (int i = 0; i < 4; ++i) {
    #pragma unroll
    for (int rr = 0; rr < 4; ++rr) {
      const int row = rb + i * 16 + rr;
      const int b = row >> 11, n = row & 2047;
      float vals[4];
      #pragma unroll
      for (int j = 0; j < 4; ++j) vals[j] = acc[i * 4 + j][rr];
      if (is_v) {
        #pragma unroll
        for (int j = 0; j < 4; ++j)
          Vt[((size_t)b * 64 + j * 16 + ln15) * 2048 + n] = (bf16_t)vals[j];
      } else {
        const float fn = (float)n;
        float s0, c0, s1, c1;
        __sincosf(fn * invf0, &s0, &c0);
        __sincosf(fn * invf1, &s1, &c1);
        #pragma unroll
        for (int j = 0; j < 4; ++j) {
          const float rot = (j < 2) ? -vals[j + 2] : vals[j - 2];
          const float c = (j & 1) ? c1 : c0;
          const float s = (j & 1) ? s1 : s0;
          const float o = vals[j] * c + rot * s;
          const int d = j * 16 + ln15;
          if (is_k)
            K[((size_t)b * 2048 + n) * 64 + d] = (bf16_t)o;
          else
            Q[(((size_t)b * 16 + hd) * 2048 + n) * 64 + d] = (bf16_t)(o * 0.125f);
        }
      }
    }
  }
}

// ---------------------------------------------------------------------------
// GEMM1b (ff): dual-B K-loop, 32 MFMA/barrier; epilogue silu(g)*x -> A2 bf16.
// ---------------------------------------------------------------------------
__global__ __launch_bounds__(256, 2) void gemm1_ff_kernel(
    const bf16_t* __restrict__ xn, const bf16_t* __restrict__ wfT,
    bf16_t* __restrict__ A2)
{
  __shared__ __align__(16) bf16_t As[128 * 32];
  __shared__ __align__(16) bf16_t Bg[128 * 32];
  __shared__ __align__(16) bf16_t Bx[128 * 32];
  const int m0 = blockIdx.x * 128;
  const int c  = blockIdx.y;
  const int t = threadIdx.x;
  const int wave = t >> 6, lane = t & 63;
  const int quad = lane >> 4, ln15 = lane & 15;
  const int wm = wave & 1, wn = wave >> 1;

  const bf16_t* gA = xn  + (size_t)(m0 + (t >> 2)) * 2048 + ((t & 3) << 3);
  const bf16_t* gG = wfT + (size_t)(9344 + c * 128 + (t >> 2)) * 2048 + ((t & 3) << 3);
  const bf16_t* gX = wfT + (size_t)(1152 + c * 128 + (t >> 2)) * 2048 + ((t & 3) << 3);
  char* lA = (char*)As + wave * 1024;
  char* lG = (char*)Bg + wave * 1024;
  char* lX = (char*)Bx + wave * 1024;
  const size_t s64 = (size_t)64 * 2048;
  const int aoff = (wm * 64 + ln15) * 32 + quad * 8;
  const int boff = (wn * 64 + ln15) * 32 + quad * 8;

  f32x4 accg[16], accx[16];
  #pragma unroll
  for (int f = 0; f < 16; ++f) {
    accg[f] = (f32x4){0.f, 0.f, 0.f, 0.f};
    accx[f] = (f32x4){0.f, 0.f, 0.f, 0.f};
  }

  for (int kt = 0; kt < 2048; kt += 32) {
    gload_lds16(gA,       lA);
    gload_lds16(gA + s64, lA + 4096);
    gload_lds16(gG,       lG);
    gload_lds16(gG + s64, lG + 4096);
    gload_lds16(gX,       lX);
    gload_lds16(gX + s64, lX + 4096);
    gA += 32; gG += 32; gX += 32;
    __syncthreads();
    bf16x8 a0 = *(const bf16x8*)(As + aoff);
    bf16x8 a1 = *(const bf16x8*)(As + aoff + 512);
    bf16x8 a2 = *(const bf16x8*)(As + aoff + 1024);
    bf16x8 a3 = *(const bf16x8*)(As + aoff + 1536);
    bf16x8 g0 = *(const bf16x8*)(Bg + boff);
    bf16x8 g1 = *(const bf16x8*)(Bg + boff + 512);
    bf16x8 g2 = *(const bf16x8*)(Bg + boff + 1024);
    bf16x8 g3 = *(const bf16x8*)(Bg + boff + 1536);
    bf16x8 x0 = *(const bf16x8*)(Bx + boff);
    bf16x8 x1 = *(const bf16x8*)(Bx + boff + 512);
    bf16x8 x2 = *(const bf16x8*)(Bx + boff + 1024);
    bf16x8 x3 = *(const bf16x8*)(Bx + boff + 1536);
    accg[0]  = mfma16(a0, g0, accg[0]);
    accg[1]  = mfma16(a0, g1, accg[1]);
    accg[2]  = mfma16(a0, g2, accg[2]);
    accg[3]  = mfma16(a0, g3, accg[3]);
    accx[0]  = mfma16(a0, x0, accx[0]);
    accx[1]  = mfma16(a0, x1, accx[1]);
    accx[2]  = mfma16(a0, x2, accx[2]);
    accx[3]  = mfma16(a0, x3, accx[3]);
    accg[4]  = mfma16(a1, g0, accg[4]);
    accg[5]  = mfma16(a1, g1, accg[5]);
    accg[6]  = mfma16(a1, g2, accg[6]);
    accg[7]  = mfma16(a1, g3, accg[7]);
    accx[4]  = mfma16(a1, x0, accx[4]);
    accx[5]  = mfma16(a1, x1, accx[5]);
    accx[6]  = mfma16(a1, x2, accx[6]);
    accx[7]  = mfma16(a1, x3, accx[7]);
    accg[8]  = mfma16(a2, g0, accg[8]);
    accg[9]  = mfma16(a2, g1, accg[9]);
    accg[10] = mfma16(a2, g2, accg[10]);
    accg[11] = mfma16(a2, g3, accg[11]);
    accx[8]  = mfma16(a2, x0, accx[8]);
    accx[9]  = mfma16(a2, x1, accx[9]);
    accx[10] = mfma16(a2, x2, accx[10]);
    accx[11] = mfma16(a2, x3, accx[11]);
    accg[12] = mfma16(a3, g0, accg[12]);
    accg[13] = mfma16(a3, g1, accg[13]);
    accg[14] = mfma16(a3, g2, accg[14]);
    accg[15] = mfma16(a3, g3, accg[15]);
    accx[12] = mfma16(a3, x0, accx[12]);
    accx[13] = mfma16(a3, x1, accx[13]);
    accx[14] = mfma16(a3, x2, accx[14]);
    accx[15] = mfma16(a3, x3, accx[15]);
    __syncthreads();
  }

  const int rb = m0 + wm * 64 + quad * 4;
  const int cb = c * 128 + wn * 64 + ln15;
  #pragma unroll
  for (int i = 0; i < 4; ++i)
    #pragma unroll
    for (int rr = 0; rr < 4; ++rr) {
      bf16_t* dst = A2 + (size_t)(rb + i * 16 + rr) * 9216 + cb;
      #pragma unroll
      for (int j = 0; j < 4; ++j) {
        const float g = accg[i * 4 + j][rr];
        const float xv = accx[i * 4 + j][rr];
        dst[j * 16] = (bf16_t)(xv * (g / (1.f + exp2f(-g * LOG2E))));
      }
    }
}

// ---------------------------------------------------------------------------
// GEMM2: out = A2(4096x9216) @ w2T^T. Dual-B (256 output cols/block) +
// split-K=2 (k-half 4608). 512 blocks, 32 MFMA/barrier. atomicAdd epilogue
// (d_out zeroed by hipMemsetAsync before launch).
// ---------------------------------------------------------------------------
__global__ __launch_bounds__(256, 2) void gemm2_kernel(
    const bf16_t* __restrict__ A2, const bf16_t* __restrict__ w2T,
    float* __restrict__ out)
{
  __shared__ __align__(16) bf16_t As[128 * 32];
  __shared__ __align__(16) bf16_t B0[128 * 32];
  __shared__ __align__(16) bf16_t B1[128 * 32];
  const int m0 = blockIdx.x * 128;
  const int n0 = blockIdx.y * 256;
  const int k0 = blockIdx.z * 4608;
  const int t = threadIdx.x;
  const int wave = t >> 6, lane = t & 63;
  const int quad = lane >> 4, ln15 = lane & 15;
  const int wm = wave & 1, wn = wave >> 1;

  const bf16_t* gA  = A2  + (size_t)(m0 + (t >> 2)) * 9216 + k0 + ((t & 3) << 3);
  const bf16_t* gB0 = w2T + (size_t)(n0 + (t >> 2)) * 9216 + k0 + ((t & 3) << 3);
  const bf16_t* gB1 = w2T + (size_t)(n0 + 128 + (t >> 2)) * 9216 + k0 + ((t & 3) << 3);
  char* lA = (char*)As + wave * 1024;
  char* l0 = (char*)B0 + wave * 1024;
  char* l1 = (char*)B1 + wave * 1024;
  const size_t s64 = (size_t)64 * 9216;
  const int aoff = (wm * 64 + ln15) * 32 + quad * 8;
  const int boff = (wn * 64 + ln15) * 32 + quad * 8;

  f32x4 acc0[16], acc1[16];
  #pragma unroll
  for (int f = 0; f < 16; ++f) {
    acc0[f] = (f32x4){0.f, 0.f, 0.f, 0.f};
    acc1[f] = (f32x4){0.f, 0.f, 0.f, 0.f};
  }

  for (int kt = 0; kt < 4608; kt += 32) {
    gload_lds16(gA,        lA);
    gload_lds16(gA + s64,  lA + 4096);
    gload_lds16(gB0,       l0);
    gload_lds16(gB0 + s64, l0 + 4096);
    gload_lds16(gB1,       l1);
    gload_lds16(gB1 + s64, l1 + 4096);
    gA += 32; gB0 += 32; gB1 += 32;
    __syncthreads();
    bf16x8 a0 = *(const bf16x8*)(As + aoff);
    bf16x8 a1 = *(const bf16x8*)(As + aoff + 512);
    bf16x8 a2 = *(const bf16x8*)(As + aoff + 1024);
    bf16x8 a3 = *(const bf16x8*)(As + aoff + 1536);
    bf16x8 p0 = *(const bf16x8*)(B0 + boff);
    bf16x8 p1 = *(const bf16x8*)(B0 + boff + 512);
    bf16x8 p2 = *(const bf16x8*)(B0 + boff + 1024);
    bf16x8 p3 = *(const bf16x8*)(B0 + boff + 1536);
    bf16x8 q0 = *(const bf16x8*)(B1 + boff);
    bf16x8 q1 = *(const bf16x8*)(B1 + boff + 512);
    bf16x8 q2 = *(const bf16x8*)(B1 + boff + 1024);
    bf16x8 q3 = *(const bf16x8*)(B1 + boff + 1536);
    acc0[0]  = mfma16(a0, p0, acc0[0]);
    acc0[1]  = mfma16(a0, p1, acc0[1]);
    acc0[2]  = mfma16(a0, p2, acc0[2]);
    acc0[3]  = mfma16(a0, p3, acc0[3]);
    acc1[0]  = mfma16(a0, q0, acc1[0]);
    acc1[1]  = mfma16(a0, q1, acc1[1]);
    acc1[2]  = mfma16(a0, q2, acc1[2]);
    acc1[3]  = mfma16(a0, q3, acc1[3]);
    acc0[4]  = mfma16(a1, p0, acc0[4]);
    acc0[5]  = mfma16(a1, p1, acc0[5]);
    acc0[6]  = mfma16(a1, p2, acc0[6]);
    acc0[7]  = mfma16(a1, p3, acc0[7]);
    acc1[4]  = mfma16(a1, q0, acc1[4]);
    acc1[5]  = mfma16(a1, q1, acc1[5]);
    acc1[6]  = mfma16(a1, q2, acc1[6]);
    acc1[7]  = mfma16(a1, q3, acc1[7]);
    acc0[8]  = mfma16(a2, p0, acc0[8]);
    acc0[9]  = mfma16(a2, p1, acc0[9]);
    acc0[10] = mfma16(a2, p2, acc0[10]);
    acc0[11] = mfma16(a2, p3, acc0[11]);
    acc1[8]  = mfma16(a2, q0, acc1[8]);
    acc1[9]  = mfma16(a2, q1, acc1[9]);
    acc1[10] = mfma16(a2, q2, acc1[10]);
    acc1[11] = mfma16(a2, q3, acc1[11]);
    acc0[12] = mfma16(a3, p0, acc0[12]);
    acc0[13] = mfma16(a3, p1, acc0[13]);
    acc0[14] = mfma16(a3, p2, acc0[14]);
    acc0[15] = mfma16(a3, p3, acc0[15]);
    acc1[12] = mfma16(a3, q0, acc1[12]);
    acc1[13] = mfma16(a3, q1, acc1[13]);
    acc1[14] = mfma16(a3, q2, acc1[14]);
    acc1[15] = mfma16(a3, q3, acc1[15]);
    __syncthreads();
  }

  const int rb = m0 + wm * 64 + quad * 4;
  #pragma unroll
  for (int half = 0; half < 2; ++half) {
    const f32x4* acc = half ? acc1 : acc0;
    const int cb = n0 + half * 128 + wn * 64 + ln15;
    #pragma unroll
    for (int i = 0; i < 4; ++i)
      #pragma unroll
      for (int rr = 0; rr < 4; ++rr) {
        float* dst = out + (size_t)(rb + i * 16 + rr) * 2048 + cb;
        #pragma unroll
        for (int j = 0; j < 4; ++j)
          unsafeAtomicAdd(dst + j * 16, acc[i * 4 + j][rr]);
      }
  }
}

// ---------------------------------------------------------------------------
// Causal MQA flash attention -> A2[:, 8192 + h*64 + d].
// Block (pidx, bh) processes Q-tiles qt=pidx and qt=15-pidx (uniform 34
// K-tiles per block).
// ---------------------------------------------------------------------------
__global__ __launch_bounds__(256) void attn_kernel(
    const bf16_t* __restrict__ Q, const bf16_t* __restrict__ Kg_,
    const bf16_t* __restrict__ Vt, bf16_t* __restrict__ A2)
{
  __shared__ __align__(16) bf16_t Qs[128 * 64];
  __shared__ __align__(16) bf16_t Ks[64 * 64];
  __shared__ __align__(16) bf16_t Vs[64 * 64];
  __shared__ __align__(16) bf16_t Ps[128 * 64];
  const int pidx = blockIdx.x, bh = blockIdx.y;
  const int b = bh >> 4, h = bh & 15;
  const int t = threadIdx.x;
  const int wave = t >> 6, lane = t & 63;
  const int quad = lane >> 4, ln15 = lane & 15;

  const bf16_t* Kg = Kg_ + (size_t)b * 2048 * 64;
  const bf16_t* Vg = Vt + (size_t)b * 64 * 2048;

  for (int hlf = 0; hlf < 2; ++hlf) {
    const int qt = hlf ? (15 - pidx) : pidx;
    const int qm0 = qt * 128;
    const bf16_t* Qg = Q + ((size_t)bh * 2048 + qm0) * 64;

    { // stage Q tile (16 KB)
      const bf16_t* g = Qg + (size_t)(t >> 3) * 64 + ((t & 7) << 3);
      char* l = (char*)Qs + wave * 1024;
      gload_lds16(g,            l);
      gload_lds16(g + 32 * 64,  l + 4096);
      gload_lds16(g + 64 * 64,  l + 8192);
      gload_lds16(g + 96 * 64,  l + 12288);
    }

    float mstate[2][4], lstate[2][4];
    f32x4 o_acc[2][4];
    #pragma unroll
    for (int i = 0; i < 2; ++i)
      #pragma unroll
      for (int rr = 0; rr < 4; ++rr) { mstate[i][rr] = -1e30f; lstate[i][rr] = 0.f; }
    #pragma unroll
    for (int i = 0; i < 2; ++i)
      #pragma unroll
      for (int jd = 0; jd < 4; ++jd) o_acc[i][jd] = (f32x4){0.f, 0.f, 0.f, 0.f};

    const int njt = qt * 2 + 2;
    for (int jt = 0; jt < njt; ++jt) {
      {
        const bf16_t* kg = Kg + (size_t)(jt * 64 + (t >> 3)) * 64 + ((t & 7) << 3);
        char* lk = (char*)Ks + wave * 1024;
        gload_lds16(kg,           lk);
        gload_lds16(kg + 32 * 64, lk + 4096);
        const bf16_t* vg = Vg + (size_t)(t >> 3) * 2048 + jt * 64 + ((t & 7) << 3);
        char* lv = (char*)Vs + wave * 1024;
        gload_lds16(vg,                   lv);
        gload_lds16(vg + (size_t)32*2048, lv + 4096);
      }
      __syncthreads();

      f32x4 sA[2][4];
      #pragma unroll
      for (int i = 0; i < 2; ++i)
        #pragma unroll
        for (int j = 0; j < 4; ++j) sA[i][j] = (f32x4){0.f, 0.f, 0.f, 0.f};
      #pragma unroll
      for (int ks = 0; ks < 2; ++ks) {
        bf16x8 aq0 = *(const bf16x8*)(Qs + (wave * 32 + ln15) * 64 + ks * 32 + quad * 8);
        bf16x8 aq1 = *(const bf16x8*)(Qs + (wave * 32 + 16 + ln15) * 64 + ks * 32 + quad * 8);
        #pragma unroll
        for (int j = 0; j < 4; ++j) {
          bf16x8 bk = *(const bf16x8*)(Ks + (j * 16 + ln15) * 64 + ks * 32 + quad * 8);
          sA[0][j] = mfma16(aq0, bk, sA[0][j]);
          sA[1][j] = mfma16(aq1, bk, sA[1][j]);
        }
      }

      const bool needmask = (jt * 64 + 63 > qm0 + wave * 32);
      #pragma unroll
      for (int i = 0; i < 2; ++i) {
        const int row0 = qm0 + wave * 32 + i * 16 + quad * 4;
        float alpha[4];
        #pragma unroll
        for (int rr = 0; rr < 4; ++rr) {
          const int rowg = row0 + rr;
          if (needmask) {
            #pragma unroll
            for (int j = 0; j < 4; ++j) {
              const int colg = jt * 64 + j * 16 + ln15;
              if (colg > rowg) sA[i][j][rr] = -1e30f;
            }
          }
          float mx = fmaxf(fmaxf(sA[i][0][rr], sA[i][1][rr]),
                           fmaxf(sA[i][2][rr], sA[i][3][rr]));
          mx = fmaxf(mx, __shfl_xor(mx, 1));
          mx = fmaxf(mx, __shfl_xor(mx, 2));
          mx = fmaxf(mx, __shfl_xor(mx, 4));
          mx = fmaxf(mx, __shfl_xor(mx, 8));
          const float mold = mstate[i][rr];
          const float mnew = fmaxf(mold, mx);
          const float al = exp2f((mold - mnew) * LOG2E);
          float rsum = 0.f;
          #pragma unroll
          for (int j = 0; j < 4; ++j) {
            const float p = exp2f((sA[i][j][rr] - mnew) * LOG2E);
            sA[i][j][rr] = p;
            rsum += p;
          }
          rsum += __shfl_xor(rsum, 1);
          rsum += __shfl_xor(rsum, 2);
          rsum += __shfl_xor(rsum, 4);
          rsum += __shfl_xor(rsum, 8);
          lstate[i][rr] = lstate[i][rr] * al + rsum;
          mstate[i][rr] = mnew;
          alpha[rr] = al;
        }
        #pragma unroll
        for (int jd = 0; jd < 4; ++jd)
          #pragma unroll
          for (int rr = 0; rr < 4; ++rr)
            o_acc[i][jd][rr] *= alpha[rr];
        #pragma unroll
        for (int j = 0; j < 4; ++j)
          #pragma unroll
          for (int rr = 0; rr < 4; ++rr)
            Ps[wave * 2048 + (i * 16 + quad * 4 + rr) * 64 + j * 16 + ln15] =
                (bf16_t)sA[i][j][rr];
      }

      #pragma unroll
      for (int ks = 0; ks < 2; ++ks) {
        bf16x8 ap0 = *(const bf16x8*)(Ps + wave * 2048 + ln15 * 64 + ks * 32 + quad * 8);
        bf16x8 ap1 = *(const bf16x8*)(Ps + wave * 2048 + (16 + ln15) * 64 + ks * 32 + quad * 8);
        #pragma unroll
        for (int jd = 0; jd < 4; ++jd) {
          bf16x8 bv = *(const bf16x8*)(Vs + (jd * 16 + ln15) * 64 + ks * 32 + quad * 8);
          o_acc[0][jd] = mfma16(ap0, bv, o_acc[0][jd]);
          o_acc[1][jd] = mfma16(ap1, bv, o_acc[1][jd]);
        }
      }
      __syncthreads();
    }

    #pragma unroll
    for (int i = 0; i < 2; ++i) {
      const int row0 = qm0 + wave * 32 + i * 16 + quad * 4;
      #pragma unroll
      for (int rr = 0; rr < 4; ++rr) {
        const float inv = 1.f / lstate[i][rr];
        bf16_t* dst = A2 + ((size_t)b * 2048 + row0 + rr) * 9216 + 8192 + h * 64 + ln15;
        #pragma unroll
        for (int jd = 0; jd < 4; ++jd)
          dst[jd * 16] = (bf16_t)(o_acc[i][jd][rr] * inv);
      }
    }
  }
}

// ---------------------------------------------------------------------------
extern "C" void kernel_launch(void* const* d_in, const int* in_sizes, int n_in,
                              void* d_out, int out_size, void* d_ws, size_t ws_size,
                              hipStream_t stream)
{
  const float* x      = (const float*)d_in[0];
  const float* gamma  = (const float*)d_in[1];
  const float* wfused = (const float*)d_in[2];
  const float* watt   = (const float*)d_in[3];
  const float* wff    = (const float*)d_in[4];
  const float* qa     = (const float*)d_in[5];
  const float* qb     = (const float*)d_in[6];
  const float* ka     = (const float*)d_in[7];
  const float* kb     = (const float*)d_in[8];
  const float* va     = (const float*)d_in[9];
  const float* vb     = (const float*)d_in[10];
  const float* oa     = (const float*)d_in[11];
  const float* ob     = (const float*)d_in[12];
  float* out = (float*)d_out;

  char* ws = (char*)d_ws;
  bf16_t* xn  = (bf16_t*)(ws);                    // 16,777,216
  bf16_t* wfT = (bf16_t*)(ws + 16777216);         // 71,827,456
  bf16_t* w2T = (bf16_t*)(ws + 88604672);         // 37,748,736
  bf16_t* A2  = (bf16_t*)(ws + 126353408);        // 75,497,472
  bf16_t* Qr  = (bf16_t*)(ws + 201850880);        //  8,388,608
  bf16_t* Kr  = (bf16_t*)(ws + 210239488);        //    524,288
  bf16_t* Vtr = (bf16_t*)(ws + 210763776);        //    524,288

  hipMemsetAsync(d_out, 0, (size_t)out_size * sizeof(float), stream);

  ln_kernel<<<dim3(4096), dim3(256), 0, stream>>>(x, gamma, xn);
  transpose_wf_kernel<<<dim3(274, 32), dim3(256), 0, stream>>>(
      wfused, qa, qb, ka, kb, va, vb, wfT);
  transpose_w2_kernel<<<dim3(32, 144), dim3(256), 0, stream>>>(
      wff, watt, oa, ob, w2T);
  gemm1_qkv_kernel<<<dim3(32, 9), dim3(256), 0, stream>>>(xn, wfT, Qr, Kr, Vtr);
  gemm1_ff_kernel<<<dim3(32, 64), dim3(256), 0, stream>>>(xn, wfT, A2);
  attn_kernel<<<dim3(8, 32), dim3(256), 0, stream>>>(Qr, Kr, Vtr, A2);
  gemm2_kernel<<<dim3(32, 8, 2), dim3(256), 0, stream>>>(A2, w2T, out);
}

// Round 4
// 967.440 us; speedup vs baseline: 1.1854x; 1.0435x over previous
//
#include <hip/hip_runtime.h>
#include <cstdint>

// ============================================================================
// ParallelTransformerBlock (PaLM-style parallel attn+FF, MQA, RoPE, LoRA)
// B=2, N=2048, DIM=2048, HEADS=16, DIM_HEAD=64 (MQA), FF_INNER=8192, R=8.
//
// R3 changes:
//  - gemm1_ff split into two half-M dispatches (perf-neutral; makes the #2
//    dispatch visible in the top-5 profile window).
//  - attn: 64-row Q-tiles, pairs (qt, 31-qt), 512 blocks (2/CU for barrier
//    hiding), uniform 33 K-tiles/block, LDS 32 KB.
//  - gemm1_qkv: dual-B (two 128-col tiles share the A tile) for the 8 q
//    col-tiles; k/v stays single-B. RoPE fused as before.
// ============================================================================

typedef __bf16 bf16_t;
typedef __bf16 bf16x8 __attribute__((ext_vector_type(8)));
typedef float f32x4 __attribute__((ext_vector_type(4)));

#define LOG2E 1.44269504088896340736f
#define LOG2_10K 13.287712379549449f   // log2(10000)

__device__ __forceinline__ void gload_lds16(const void* g, void* l) {
  __builtin_amdgcn_global_load_lds(
      (__attribute__((address_space(1))) void*)(uintptr_t)g,
      (__attribute__((address_space(3))) void*)(uint32_t)(uintptr_t)l,
      16, 0, 0);
}

__device__ __forceinline__ f32x4 mfma16(bf16x8 a, bf16x8 b, f32x4 c) {
  return __builtin_amdgcn_mfma_f32_16x16x32_bf16(a, b, c, 0, 0, 0);
}

// ---------------------------------------------------------------------------
// LayerNorm: one block per token row (4096 rows x 2048)
// ---------------------------------------------------------------------------
__global__ __launch_bounds__(256) void ln_kernel(
    const float* __restrict__ x, const float* __restrict__ gamma,
    bf16_t* __restrict__ xn)
{
  const int row = blockIdx.x;
  const int t = threadIdx.x;
  const float4* xr = (const float4*)(x + (size_t)row * 2048);
  float4 a = xr[t * 2];
  float4 b = xr[t * 2 + 1];
  float s  = a.x + a.y + a.z + a.w + b.x + b.y + b.z + b.w;
  float ss = a.x*a.x + a.y*a.y + a.z*a.z + a.w*a.w
           + b.x*b.x + b.y*b.y + b.z*b.z + b.w*b.w;
  #pragma unroll
  for (int m = 1; m < 64; m <<= 1) {
    s  += __shfl_xor(s, m);
    ss += __shfl_xor(ss, m);
  }
  __shared__ float red[8];
  const int wave = t >> 6, lane = t & 63;
  if (lane == 0) { red[wave] = s; red[4 + wave] = ss; }
  __syncthreads();
  const float stot  = red[0] + red[1] + red[2] + red[3];
  const float sstot = red[4] + red[5] + red[6] + red[7];
  const float mu  = stot * (1.f / 2048.f);
  const float var = sstot * (1.f / 2048.f) - mu * mu;
  const float rs  = rsqrtf(var + 1e-5f);
  float v[8] = {a.x, a.y, a.z, a.w, b.x, b.y, b.z, b.w};
  bf16x8 o;
  #pragma unroll
  for (int e = 0; e < 8; ++e)
    o[e] = (bf16_t)((v[e] - mu) * rs * gamma[t * 8 + e]);
  *(bf16x8*)(xn + (size_t)row * 2048 + t * 8) = o;
}

// ---------------------------------------------------------------------------
// Transpose+convert w_fused (2048 x 17536 f32) -> wfT (17536 x 2048 bf16),
// folding lora_q/k/v into cols [0,1152). 64x64 tiles, LDS pad +1.
// ---------------------------------------------------------------------------
__global__ __launch_bounds__(256) void transpose_wf_kernel(
    const float* __restrict__ w,
    const float* __restrict__ qa, const float* __restrict__ qb,
    const float* __restrict__ ka, const float* __restrict__ kb,
    const float* __restrict__ va, const float* __restrict__ vb,
    bf16_t* __restrict__ wfT)
{
  __shared__ float tile[64][65];
  const int t  = threadIdx.x;
  const int n0 = blockIdx.x * 64;
  const int k0 = blockIdx.y * 64;
  #pragma unroll
  for (int it = 0; it < 4; ++it) {
    const int kr = (t >> 4) + it * 16;
    const float4 vv = *(const float4*)(w + (size_t)(k0 + kr) * 17536 + n0 + (t & 15) * 4);
    tile[kr][(t & 15) * 4 + 0] = vv.x;
    tile[kr][(t & 15) * 4 + 1] = vv.y;
    tile[kr][(t & 15) * 4 + 2] = vv.z;
    tile[kr][(t & 15) * 4 + 3] = vv.w;
  }
  __syncthreads();
  const float* la = nullptr; const float* lb = nullptr;
  int nbo = 0, ldlb = 0;
  if (n0 < 1024)      { la = qa; lb = qb; nbo = n0;        ldlb = 1024; }
  else if (n0 < 1088) { la = ka; lb = kb; nbo = n0 - 1024; ldlb = 64;   }
  else if (n0 < 1152) { la = va; lb = vb; nbo = n0 - 1088; ldlb = 64;   }
  #pragma unroll
  for (int it = 0; it < 2; ++it) {
    const int nl = (t >> 3) + it * 32;
    const int kl = (t & 7) * 8;
    float vals[8];
    #pragma unroll
    for (int e = 0; e < 8; ++e) vals[e] = tile[kl + e][nl];
    if (la) {
      float bc[8];
      #pragma unroll
      for (int r = 0; r < 8; ++r) bc[r] = lb[r * ldlb + nbo + nl];
      #pragma unroll
      for (int e = 0; e < 8; ++e) {
        const float* ar = la + (size_t)(k0 + kl + e) * 8;
        float d = 0.f;
        #pragma unroll
        for (int r = 0; r < 8; ++r) d += ar[r] * bc[r];
        vals[e] += d;
      }
    }
    bf16x8 o;
    #pragma unroll
    for (int e = 0; e < 8; ++e) o[e] = (bf16_t)vals[e];
    *(bf16x8*)(wfT + (size_t)(n0 + nl) * 2048 + k0 + kl) = o;
  }
}

// ---------------------------------------------------------------------------
// Build w2T (2048 x 9216 bf16): cols [0,8192) = w_ff_out^T,
// cols [8192,9216) = (w_attn_out + lora_o_a@lora_o_b)^T.
// ---------------------------------------------------------------------------
__global__ __launch_bounds__(256) void transpose_w2_kernel(
    const float* __restrict__ wff,   // 8192 x 2048
    const float* __restrict__ watt,  // 1024 x 2048
    const float* __restrict__ oa, const float* __restrict__ ob,
    bf16_t* __restrict__ w2T)
{
  __shared__ float tile[64][65];
  const int t  = threadIdx.x;
  const int n0 = blockIdx.x * 64;
  const int k0 = blockIdx.y * 64;          // 0..9152
  const bool isatt = (k0 >= 8192);
  const float* src = isatt ? (watt + (size_t)(k0 - 8192) * 2048)
                           : (wff + (size_t)k0 * 2048);
  #pragma unroll
  for (int it = 0; it < 4; ++it) {
    const int kr = (t >> 4) + it * 16;
    const float4 vv = *(const float4*)(src + (size_t)kr * 2048 + n0 + (t & 15) * 4);
    tile[kr][(t & 15) * 4 + 0] = vv.x;
    tile[kr][(t & 15) * 4 + 1] = vv.y;
    tile[kr][(t & 15) * 4 + 2] = vv.z;
    tile[kr][(t & 15) * 4 + 3] = vv.w;
  }
  __syncthreads();
  #pragma unroll
  for (int it = 0; it < 2; ++it) {
    const int nl = (t >> 3) + it * 32;
    const int kl = (t & 7) * 8;
    float vals[8];
    #pragma unroll
    for (int e = 0; e < 8; ++e) vals[e] = tile[kl + e][nl];
    if (isatt) {
      float bc[8];
      #pragma unroll
      for (int r = 0; r < 8; ++r) bc[r] = ob[r * 2048 + n0 + nl];
      #pragma unroll
      for (int e = 0; e < 8; ++e) {
        const float* ar = oa + (size_t)(k0 - 8192 + kl + e) * 8;
        float d = 0.f;
        #pragma unroll
        for (int r = 0; r < 8; ++r) d += ar[r] * bc[r];
        vals[e] += d;
      }
    }
    bf16x8 o;
    #pragma unroll
    for (int e = 0; e < 8; ++e) o[e] = (bf16_t)vals[e];
    *(bf16x8*)(w2T + (size_t)(n0 + nl) * 9216 + k0 + kl) = o;
  }
}

// ---------------------------------------------------------------------------
// Single-B GEMM core: C[128x128] += A * BT^T (16 MFMA/barrier).
// ---------------------------------------------------------------------------
__device__ __forceinline__ void gemm_core_128x128(
    const bf16_t* __restrict__ A, int ldA, int m0,
    const bf16_t* __restrict__ BT, int ldB, int n0,
    int K, bf16_t* As, bf16_t* Bs, f32x4* acc)
{
  const int t = threadIdx.x;
  const int wave = t >> 6;
  const int lane = t & 63;
  const int quad = lane >> 4;
  const int ln15 = lane & 15;
  const int wm = wave & 1, wn = wave >> 1;

  const bf16_t* gA = A + (size_t)(m0 + (t >> 2)) * ldA + ((t & 3) << 3);
  const bf16_t* gB = BT + (size_t)(n0 + (t >> 2)) * ldB + ((t & 3) << 3);
  char* lA = (char*)As + wave * 1024;
  char* lB = (char*)Bs + wave * 1024;
  const size_t sA64 = (size_t)64 * ldA;
  const size_t sB64 = (size_t)64 * ldB;
  const int aoff = (wm * 64 + ln15) * 32 + quad * 8;
  const int boff = (wn * 64 + ln15) * 32 + quad * 8;

  for (int kt = 0; kt < K; kt += 32) {
    gload_lds16(gA,        lA);
    gload_lds16(gA + sA64, lA + 4096);
    gload_lds16(gB,        lB);
    gload_lds16(gB + sB64, lB + 4096);
    gA += 32;
    gB += 32;
    __syncthreads();
    bf16x8 a0 = *(const bf16x8*)(As + aoff);
    bf16x8 a1 = *(const bf16x8*)(As + aoff + 512);
    bf16x8 a2 = *(const bf16x8*)(As + aoff + 1024);
    bf16x8 a3 = *(const bf16x8*)(As + aoff + 1536);
    bf16x8 b0 = *(const bf16x8*)(Bs + boff);
    bf16x8 b1 = *(const bf16x8*)(Bs + boff + 512);
    bf16x8 b2 = *(const bf16x8*)(Bs + boff + 1024);
    bf16x8 b3 = *(const bf16x8*)(Bs + boff + 1536);
    acc[0]  = mfma16(a0, b0, acc[0]);
    acc[1]  = mfma16(a0, b1, acc[1]);
    acc[2]  = mfma16(a0, b2, acc[2]);
    acc[3]  = mfma16(a0, b3, acc[3]);
    acc[4]  = mfma16(a1, b0, acc[4]);
    acc[5]  = mfma16(a1, b1, acc[5]);
    acc[6]  = mfma16(a1, b2, acc[6]);
    acc[7]  = mfma16(a1, b3, acc[7]);
    acc[8]  = mfma16(a2, b0, acc[8]);
    acc[9]  = mfma16(a2, b1, acc[9]);
    acc[10] = mfma16(a2, b2, acc[10]);
    acc[11] = mfma16(a2, b3, acc[11]);
    acc[12] = mfma16(a3, b0, acc[12]);
    acc[13] = mfma16(a3, b1, acc[13]);
    acc[14] = mfma16(a3, b2, acc[14]);
    acc[15] = mfma16(a3, b3, acc[15]);
    __syncthreads();
  }
}

// ---------------------------------------------------------------------------
// Dual-B GEMM core: one A tile, two B tiles, 32 MFMA/barrier.
// gA/gB0/gB1 pre-offset to (row_base + t>>2, (t&3)*8).
// ---------------------------------------------------------------------------
__device__ __forceinline__ void gemm_core_dual(
    const bf16_t* gA, const bf16_t* gB0, const bf16_t* gB1,
    int ldA, int ldB, int K,
    bf16_t* As, bf16_t* B0s, bf16_t* B1s,
    f32x4* acc0, f32x4* acc1)
{
  const int t = threadIdx.x;
  const int wave = t >> 6;
  const int lane = t & 63;
  const int quad = lane >> 4;
  const int ln15 = lane & 15;
  const int wm = wave & 1, wn = wave >> 1;

  char* lA = (char*)As + wave * 1024;
  char* l0 = (char*)B0s + wave * 1024;
  char* l1 = (char*)B1s + wave * 1024;
  const size_t sA64 = (size_t)64 * ldA;
  const size_t sB64 = (size_t)64 * ldB;
  const int aoff = (wm * 64 + ln15) * 32 + quad * 8;
  const int boff = (wn * 64 + ln15) * 32 + quad * 8;

  for (int kt = 0; kt < K; kt += 32) {
    gload_lds16(gA,         lA);
    gload_lds16(gA + sA64,  lA + 4096);
    gload_lds16(gB0,        l0);
    gload_lds16(gB0 + sB64, l0 + 4096);
    gload_lds16(gB1,        l1);
    gload_lds16(gB1 + sB64, l1 + 4096);
    gA += 32; gB0 += 32; gB1 += 32;
    __syncthreads();
    bf16x8 a0 = *(const bf16x8*)(As + aoff);
    bf16x8 a1 = *(const bf16x8*)(As + aoff + 512);
    bf16x8 a2 = *(const bf16x8*)(As + aoff + 1024);
    bf16x8 a3 = *(const bf16x8*)(As + aoff + 1536);
    bf16x8 p0 = *(const bf16x8*)(B0s + boff);
    bf16x8 p1 = *(const bf16x8*)(B0s + boff + 512);
    bf16x8 p2 = *(const bf16x8*)(B0s + boff + 1024);
    bf16x8 p3 = *(const bf16x8*)(B0s + boff + 1536);
    bf16x8 q0 = *(const bf16x8*)(B1s + boff);
    bf16x8 q1 = *(const bf16x8*)(B1s + boff + 512);
    bf16x8 q2 = *(const bf16x8*)(B1s + boff + 1024);
    bf16x8 q3 = *(const bf16x8*)(B1s + boff + 1536);
    acc0[0]  = mfma16(a0, p0, acc0[0]);
    acc0[1]  = mfma16(a0, p1, acc0[1]);
    acc0[2]  = mfma16(a0, p2, acc0[2]);
    acc0[3]  = mfma16(a0, p3, acc0[3]);
    acc1[0]  = mfma16(a0, q0, acc1[0]);
    acc1[1]  = mfma16(a0, q1, acc1[1]);
    acc1[2]  = mfma16(a0, q2, acc1[2]);
    acc1[3]  = mfma16(a0, q3, acc1[3]);
    acc0[4]  = mfma16(a1, p0, acc0[4]);
    acc0[5]  = mfma16(a1, p1, acc0[5]);
    acc0[6]  = mfma16(a1, p2, acc0[6]);
    acc0[7]  = mfma16(a1, p3, acc0[7]);
    acc1[4]  = mfma16(a1, q0, acc1[4]);
    acc1[5]  = mfma16(a1, q1, acc1[5]);
    acc1[6]  = mfma16(a1, q2, acc1[6]);
    acc1[7]  = mfma16(a1, q3, acc1[7]);
    acc0[8]  = mfma16(a2, p0, acc0[8]);
    acc0[9]  = mfma16(a2, p1, acc0[9]);
    acc0[10] = mfma16(a2, p2, acc0[10]);
    acc0[11] = mfma16(a2, p3, acc0[11]);
    acc1[8]  = mfma16(a2, q0, acc1[8]);
    acc1[9]  = mfma16(a2, q1, acc1[9]);
    acc1[10] = mfma16(a2, q2, acc1[10]);
    acc1[11] = mfma16(a2, q3, acc1[11]);
    acc0[12] = mfma16(a3, p0, acc0[12]);
    acc0[13] = mfma16(a3, p1, acc0[13]);
    acc0[14] = mfma16(a3, p2, acc0[14]);
    acc0[15] = mfma16(a3, p3, acc0[15]);
    acc1[12] = mfma16(a3, q0, acc1[12]);
    acc1[13] = mfma16(a3, q1, acc1[13]);
    acc1[14] = mfma16(a3, q2, acc1[14]);
    acc1[15] = mfma16(a3, q3, acc1[15]);
    __syncthreads();
  }
}

// ---------------------------------------------------------------------------
// GEMM1a (qkv cols 0..1151), RoPE + layout fused.
// y<4: dual-B q pair (cols y*256, +128); heads y*4 + half*2 + wn.
// y==4: single-B at col 1024; wn=0 -> k, wn=1 -> v.
// ---------------------------------------------------------------------------
__global__ __launch_bounds__(256, 2) void gemm1_qkv_kernel(
    const bf16_t* __restrict__ xn, const bf16_t* __restrict__ wfT,
    bf16_t* __restrict__ Q, bf16_t* __restrict__ K, bf16_t* __restrict__ Vt)
{
  __shared__ __align__(16) bf16_t As[128 * 32];
  __shared__ __align__(16) bf16_t B0s[128 * 32];
  __shared__ __align__(16) bf16_t B1s[128 * 32];
  const int m0 = blockIdx.x * 128;
  const int y = blockIdx.y;
  const int t = threadIdx.x;
  const int wave = t >> 6, lane = t & 63;
  const int quad = lane >> 4, ln15 = lane & 15;
  const int wm = wave & 1, wn = wave >> 1;

  const int rb = m0 + wm * 64 + quad * 4;
  const float invf0 = exp2f(-(float)ln15 * (LOG2_10K / 32.0f));
  const float invf1 = exp2f(-(float)(16 + ln15) * (LOG2_10K / 32.0f));

  if (y < 4) {
    const bf16_t* gA  = xn  + (size_t)(m0 + (t >> 2)) * 2048 + ((t & 3) << 3);
    const bf16_t* gB0 = wfT + (size_t)(y * 256 + (t >> 2)) * 2048 + ((t & 3) << 3);
    const bf16_t* gB1 = wfT + (size_t)(y * 256 + 128 + (t >> 2)) * 2048 + ((t & 3) << 3);
    f32x4 acc0[16], acc1[16];
    #pragma unroll
    for (int f = 0; f < 16; ++f) {
      acc0[f] = (f32x4){0.f, 0.f, 0.f, 0.f};
      acc1[f] = (f32x4){0.f, 0.f, 0.f, 0.f};
    }
    gemm_core_dual(gA, gB0, gB1, 2048, 2048, 2048, As, B0s, B1s, acc0, acc1);
    #pragma unroll
    for (int half = 0; half < 2; ++half) {
      const f32x4* acc = half ? acc1 : acc0;
      const int hd = y * 4 + half * 2 + wn;
      #pragma unroll
      for (int i = 0; i < 4; ++i) {
        #pragma unroll
        for (int rr = 0; rr < 4; ++rr) {
          const int row = rb + i * 16 + rr;
          const int b = row >> 11, n = row & 2047;
          const float fn = (float)n;
          float s0, c0, s1, c1;
          __sincosf(fn * invf0, &s0, &c0);
          __sincosf(fn * invf1, &s1, &c1);
          float vals[4];
          #pragma unroll
          for (int j = 0; j < 4; ++j) vals[j] = acc[i * 4 + j][rr];
          #pragma unroll
          for (int j = 0; j < 4; ++j) {
            const float rot = (j < 2) ? -vals[j + 2] : vals[j - 2];
            const float c = (j & 1) ? c1 : c0;
            const float s = (j & 1) ? s1 : s0;
            const float o = (vals[j] * c + rot * s) * 0.125f;
            Q[(((size_t)b * 16 + hd) * 2048 + n) * 64 + j * 16 + ln15] = (bf16_t)o;
          }
        }
      }
    }
  } else {
    f32x4 acc[16];
    #pragma unroll
    for (int f = 0; f < 16; ++f) acc[f] = (f32x4){0.f, 0.f, 0.f, 0.f};
    gemm_core_128x128(xn, 2048, m0, wfT, 2048, 1024, 2048, As, B0s, acc);
    const bool is_k = (wn == 0);
    #pragma unroll
    for (int i = 0; i < 4; ++i) {
      #pragma unroll
      for (int rr = 0; rr < 4; ++rr) {
        const int row = rb + i * 16 + rr;
        const int b = row >> 11, n = row & 2047;
        float vals[4];
        #pragma unroll
        for (int j = 0; j < 4; ++j) vals[j] = acc[i * 4 + j][rr];
        if (is_k) {
          const float fn = (float)n;
          float s0, c0, s1, c1;
          __sincosf(fn * invf0, &s0, &c0);
          __sincosf(fn * invf1, &s1, &c1);
          #pragma unroll
          for (int j = 0; j < 4; ++j) {
            const float rot = (j < 2) ? -vals[j + 2] : vals[j - 2];
            const float c = (j & 1) ? c1 : c0;
            const float s = (j & 1) ? s1 : s0;
            K[((size_t)b * 2048 + n) * 64 + j * 16 + ln15] = (bf16_t)(vals[j] * c + rot * s);
          }
        } else {
          #pragma unroll
          for (int j = 0; j < 4; ++j)
            Vt[((size_t)b * 64 + j * 16 + ln15) * 2048 + n] = (bf16_t)vals[j];
        }
      }
    }
  }
}

// ---------------------------------------------------------------------------
// GEMM1b (ff): dual-B (gate + x), silu fused. Half-M per dispatch (m_base).
// ---------------------------------------------------------------------------
__global__ __launch_bounds__(256, 2) void gemm1_ff_kernel(
    const bf16_t* __restrict__ xn, const bf16_t* __restrict__ wfT,
    bf16_t* __restrict__ A2, int m_base)
{
  __shared__ __align__(16) bf16_t As[128 * 32];
  __shared__ __align__(16) bf16_t Bg[128 * 32];
  __shared__ __align__(16) bf16_t Bx[128 * 32];
  const int m0 = m_base + blockIdx.x * 128;
  const int c  = blockIdx.y;
  const int t = threadIdx.x;
  const int wave = t >> 6, lane = t & 63;
  const int quad = lane >> 4, ln15 = lane & 15;
  const int wm = wave & 1, wn = wave >> 1;

  const bf16_t* gA = xn  + (size_t)(m0 + (t >> 2)) * 2048 + ((t & 3) << 3);
  const bf16_t* gG = wfT + (size_t)(9344 + c * 128 + (t >> 2)) * 2048 + ((t & 3) << 3);
  const bf16_t* gX = wfT + (size_t)(1152 + c * 128 + (t >> 2)) * 2048 + ((t & 3) << 3);

  f32x4 accg[16], accx[16];
  #pragma unroll
  for (int f = 0; f < 16; ++f) {
    accg[f] = (f32x4){0.f, 0.f, 0.f, 0.f};
    accx[f] = (f32x4){0.f, 0.f, 0.f, 0.f};
  }
  gemm_core_dual(gA, gG, gX, 2048, 2048, 2048, As, Bg, Bx, accg, accx);

  const int rb = m0 + wm * 64 + quad * 4;
  const int cb = c * 128 + wn * 64 + ln15;
  #pragma unroll
  for (int i = 0; i < 4; ++i)
    #pragma unroll
    for (int rr = 0; rr < 4; ++rr) {
      bf16_t* dst = A2 + (size_t)(rb + i * 16 + rr) * 9216 + cb;
      #pragma unroll
      for (int j = 0; j < 4; ++j) {
        const float g = accg[i * 4 + j][rr];
        const float xv = accx[i * 4 + j][rr];
        dst[j * 16] = (bf16_t)(xv * (g / (1.f + exp2f(-g * LOG2E))));
      }
    }
}

// ---------------------------------------------------------------------------
// GEMM2: out = A2(4096x9216) @ w2T^T. Dual-B + split-K=2, atomicAdd epilogue.
// ---------------------------------------------------------------------------
__global__ __launch_bounds__(256, 2) void gemm2_kernel(
    const bf16_t* __restrict__ A2, const bf16_t* __restrict__ w2T,
    float* __restrict__ out)
{
  __shared__ __align__(16) bf16_t As[128 * 32];
  __shared__ __align__(16) bf16_t B0[128 * 32];
  __shared__ __align__(16) bf16_t B1[128 * 32];
  const int m0 = blockIdx.x * 128;
  const int n0 = blockIdx.y * 256;
  const int k0 = blockIdx.z * 4608;
  const int t = threadIdx.x;
  const int wave = t >> 6, lane = t & 63;
  const int quad = lane >> 4, ln15 = lane & 15;
  const int wm = wave & 1, wn = wave >> 1;

  const bf16_t* gA  = A2  + (size_t)(m0 + (t >> 2)) * 9216 + k0 + ((t & 3) << 3);
  const bf16_t* gB0 = w2T + (size_t)(n0 + (t >> 2)) * 9216 + k0 + ((t & 3) << 3);
  const bf16_t* gB1 = w2T + (size_t)(n0 + 128 + (t >> 2)) * 9216 + k0 + ((t & 3) << 3);

  f32x4 acc0[16], acc1[16];
  #pragma unroll
  for (int f = 0; f < 16; ++f) {
    acc0[f] = (f32x4){0.f, 0.f, 0.f, 0.f};
    acc1[f] = (f32x4){0.f, 0.f, 0.f, 0.f};
  }
  gemm_core_dual(gA, gB0, gB1, 9216, 9216, 4608, As, B0, B1, acc0, acc1);

  const int rb = m0 + wm * 64 + quad * 4;
  #pragma unroll
  for (int half = 0; half < 2; ++half) {
    const f32x4* acc = half ? acc1 : acc0;
    const int cb = n0 + half * 128 + wn * 64 + ln15;
    #pragma unroll
    for (int i = 0; i < 4; ++i)
      #pragma unroll
      for (int rr = 0; rr < 4; ++rr) {
        float* dst = out + (size_t)(rb + i * 16 + rr) * 2048 + cb;
        #pragma unroll
        for (int j = 0; j < 4; ++j)
          unsafeAtomicAdd(dst + j * 16, acc[i * 4 + j][rr]);
      }
  }
}

// ---------------------------------------------------------------------------
// Causal MQA flash attention -> A2[:, 8192 + h*64 + d].
// Block (p, bh): Q-tiles qt=p and qt=31-p, 64 rows each; uniform 33 K-tiles.
// 512 blocks, LDS 32 KB (2+ blocks/CU for barrier hiding).
// ---------------------------------------------------------------------------
__global__ __launch_bounds__(256, 2) void attn_kernel(
    const bf16_t* __restrict__ Q, const bf16_t* __restrict__ Kg_,
    const bf16_t* __restrict__ Vt, bf16_t* __restrict__ A2)
{
  __shared__ __align__(16) bf16_t Qs[64 * 64];
  __shared__ __align__(16) bf16_t Ks[64 * 64];
  __shared__ __align__(16) bf16_t Vs[64 * 64];
  __shared__ __align__(16) bf16_t Ps[64 * 64];
  const int pidx = blockIdx.x, bh = blockIdx.y;
  const int b = bh >> 4, h = bh & 15;
  const int t = threadIdx.x;
  const int wave = t >> 6, lane = t & 63;
  const int quad = lane >> 4, ln15 = lane & 15;

  const bf16_t* Kg = Kg_ + (size_t)b * 2048 * 64;
  const bf16_t* Vg = Vt + (size_t)b * 64 * 2048;

  for (int hlf = 0; hlf < 2; ++hlf) {
    const int qt = hlf ? (31 - pidx) : pidx;
    const int qm0 = qt * 64;
    const bf16_t* Qg = Q + ((size_t)bh * 2048 + qm0) * 64;

    { // stage Q tile (8 KB, 2 rounds)
      const bf16_t* g = Qg + (size_t)(t >> 3) * 64 + ((t & 7) << 3);
      char* l = (char*)Qs + wave * 1024;
      gload_lds16(g,           l);
      gload_lds16(g + 32 * 64, l + 4096);
    }

    float mstate[4], lstate[4];
    f32x4 o_acc[4];
    #pragma unroll
    for (int rr = 0; rr < 4; ++rr) { mstate[rr] = -1e30f; lstate[rr] = 0.f; }
    #pragma unroll
    for (int jd = 0; jd < 4; ++jd) o_acc[jd] = (f32x4){0.f, 0.f, 0.f, 0.f};

    const int njt = qt + 1;
    for (int jt = 0; jt < njt; ++jt) {
      { // stage K, V tiles (8 KB each)
        const bf16_t* kg = Kg + (size_t)(jt * 64 + (t >> 3)) * 64 + ((t & 7) << 3);
        char* lk = (char*)Ks + wave * 1024;
        gload_lds16(kg,           lk);
        gload_lds16(kg + 32 * 64, lk + 4096);
        const bf16_t* vg = Vg + (size_t)(t >> 3) * 2048 + jt * 64 + ((t & 7) << 3);
        char* lv = (char*)Vs + wave * 1024;
        gload_lds16(vg,                   lv);
        gload_lds16(vg + (size_t)32*2048, lv + 4096);
      }
      __syncthreads();

      f32x4 sA[4];
      #pragma unroll
      for (int j = 0; j < 4; ++j) sA[j] = (f32x4){0.f, 0.f, 0.f, 0.f};
      #pragma unroll
      for (int ks = 0; ks < 2; ++ks) {
        bf16x8 aq = *(const bf16x8*)(Qs + (wave * 16 + ln15) * 64 + ks * 32 + quad * 8);
        #pragma unroll
        for (int j = 0; j < 4; ++j) {
          bf16x8 bk = *(const bf16x8*)(Ks + (j * 16 + ln15) * 64 + ks * 32 + quad * 8);
          sA[j] = mfma16(aq, bk, sA[j]);
        }
      }

      const bool needmask = (jt * 64 + 63 > qm0 + wave * 16);
      const int row0 = qm0 + wave * 16 + quad * 4;
      float alpha[4];
      #pragma unroll
      for (int rr = 0; rr < 4; ++rr) {
        const int rowg = row0 + rr;
        if (needmask) {
          #pragma unroll
          for (int j = 0; j < 4; ++j) {
            const int colg = jt * 64 + j * 16 + ln15;
            if (colg > rowg) sA[j][rr] = -1e30f;
          }
        }
        float mx = fmaxf(fmaxf(sA[0][rr], sA[1][rr]),
                         fmaxf(sA[2][rr], sA[3][rr]));
        mx = fmaxf(mx, __shfl_xor(mx, 1));
        mx = fmaxf(mx, __shfl_xor(mx, 2));
        mx = fmaxf(mx, __shfl_xor(mx, 4));
        mx = fmaxf(mx, __shfl_xor(mx, 8));
        const float mold = mstate[rr];
        const float mnew = fmaxf(mold, mx);
        const float al = exp2f((mold - mnew) * LOG2E);
        float rsum = 0.f;
        #pragma unroll
        for (int j = 0; j < 4; ++j) {
          const float p = exp2f((sA[j][rr] - mnew) * LOG2E);
          sA[j][rr] = p;
          rsum += p;
        }
        rsum += __shfl_xor(rsum, 1);
        rsum += __shfl_xor(rsum, 2);
        rsum += __shfl_xor(rsum, 4);
        rsum += __shfl_xor(rsum, 8);
        lstate[rr] = lstate[rr] * al + rsum;
        mstate[rr] = mnew;
        alpha[rr] = al;
      }
      #pragma unroll
      for (int jd = 0; jd < 4; ++jd)
        #pragma unroll
        for (int rr = 0; rr < 4; ++rr)
          o_acc[jd][rr] *= alpha[rr];
      #pragma unroll
      for (int j = 0; j < 4; ++j)
        #pragma unroll
        for (int rr = 0; rr < 4; ++rr)
          Ps[wave * 1024 + (quad * 4 + rr) * 64 + j * 16 + ln15] = (bf16_t)sA[j][rr];

      #pragma unroll
      for (int ks = 0; ks < 2; ++ks) {
        bf16x8 ap = *(const bf16x8*)(Ps + wave * 1024 + ln15 * 64 + ks * 32 + quad * 8);
        #pragma unroll
        for (int jd = 0; jd < 4; ++jd) {
          bf16x8 bv = *(const bf16x8*)(Vs + (jd * 16 + ln15) * 64 + ks * 32 + quad * 8);
          o_acc[jd] = mfma16(ap, bv, o_acc[jd]);
        }
      }
      __syncthreads();
    }

    const int row0 = qm0 + wave * 16 + quad * 4;
    #pragma unroll
    for (int rr = 0; rr < 4; ++rr) {
      const float inv = 1.f / lstate[rr];
      bf16_t* dst = A2 + ((size_t)b * 2048 + row0 + rr) * 9216 + 8192 + h * 64 + ln15;
      #pragma unroll
      for (int jd = 0; jd < 4; ++jd)
        dst[jd * 16] = (bf16_t)(o_acc[jd][rr] * inv);
    }
  }
}

// ---------------------------------------------------------------------------
extern "C" void kernel_launch(void* const* d_in, const int* in_sizes, int n_in,
                              void* d_out, int out_size, void* d_ws, size_t ws_size,
                              hipStream_t stream)
{
  const float* x      = (const float*)d_in[0];
  const float* gamma  = (const float*)d_in[1];
  const float* wfused = (const float*)d_in[2];
  const float* watt   = (const float*)d_in[3];
  const float* wff    = (const float*)d_in[4];
  const float* qa     = (const float*)d_in[5];
  const float* qb     = (const float*)d_in[6];
  const float* ka     = (const float*)d_in[7];
  const float* kb     = (const float*)d_in[8];
  const float* va     = (const float*)d_in[9];
  const float* vb     = (const float*)d_in[10];
  const float* oa     = (const float*)d_in[11];
  const float* ob     = (const float*)d_in[12];
  float* out = (float*)d_out;

  char* ws = (char*)d_ws;
  bf16_t* xn  = (bf16_t*)(ws);                    // 16,777,216
  bf16_t* wfT = (bf16_t*)(ws + 16777216);         // 71,827,456
  bf16_t* w2T = (bf16_t*)(ws + 88604672);         // 37,748,736
  bf16_t* A2  = (bf16_t*)(ws + 126353408);        // 75,497,472
  bf16_t* Qr  = (bf16_t*)(ws + 201850880);        //  8,388,608
  bf16_t* Kr  = (bf16_t*)(ws + 210239488);        //    524,288
  bf16_t* Vtr = (bf16_t*)(ws + 210763776);        //    524,288

  hipMemsetAsync(d_out, 0, (size_t)out_size * sizeof(float), stream);

  ln_kernel<<<dim3(4096), dim3(256), 0, stream>>>(x, gamma, xn);
  transpose_wf_kernel<<<dim3(274, 32), dim3(256), 0, stream>>>(
      wfused, qa, qb, ka, kb, va, vb, wfT);
  transpose_w2_kernel<<<dim3(32, 144), dim3(256), 0, stream>>>(
      wff, watt, oa, ob, w2T);
  gemm1_qkv_kernel<<<dim3(32, 5), dim3(256), 0, stream>>>(xn, wfT, Qr, Kr, Vtr);
  gemm1_ff_kernel<<<dim3(16, 64), dim3(256), 0, stream>>>(xn, wfT, A2, 0);
  gemm1_ff_kernel<<<dim3(16, 64), dim3(256), 0, stream>>>(xn, wfT, A2, 2048);
  attn_kernel<<<dim3(16, 32), dim3(256), 0, stream>>>(Qr, Kr, Vtr, A2);
  gemm2_kernel<<<dim3(32, 8, 2), dim3(256), 0, stream>>>(A2, w2T, out);
}